// Round 1
// baseline (1189.485 us; speedup 1.0000x reference)
//
#include <hip/hip_runtime.h>
#include <cstdint>
#include <cstddef>

#define BB   16
#define NN   8192
#define DD   64
#define MM   256
#define SS   32
#define OUTC 128
#define WCC  64

__device__ __forceinline__ float bnf(float x, float g, float be){
    const float BNS = 0.99999500003749969f; // 1/sqrt(1+1e-5)
    return g * (x * BNS) + be;
}

// ---------------- feature transpose (B,D,N) -> (B,N,D) ----------------
__global__ __launch_bounds__(256) void k_tf(const float* __restrict__ f, float* __restrict__ fT){
  const int blk = blockIdx.x;
  const int b  = blk >> 7;
  const int n0 = (blk & 127) << 6;
  __shared__ float tile[64][65];
  const int t = threadIdx.x;
  {
    const int d = t >> 2, j0 = (t & 3) << 4;
    const float* src = f + ((size_t)b*DD + d)*NN + n0 + j0;
#pragma unroll
    for (int i=0;i<16;i+=4){
      float4 v = *(const float4*)(src + i);
      tile[d][j0+i+0]=v.x; tile[d][j0+i+1]=v.y; tile[d][j0+i+2]=v.z; tile[d][j0+i+3]=v.w;
    }
  }
  __syncthreads();
  {
    const int j = t >> 2, d0 = (t & 3) << 4;
    float* dst = fT + ((size_t)b*NN + n0 + j)*DD + d0;
#pragma unroll
    for (int i=0;i<16;i+=4){
      float4 v = make_float4(tile[d0+i][j], tile[d0+i+1][j], tile[d0+i+2][j], tile[d0+i+3][j]);
      *(float4*)(dst + i) = v;
    }
  }
}

// ---------------- small weight transposes ----------------
__global__ __launch_bounds__(256) void k_twl(const float* __restrict__ wl, float* __restrict__ wlT){
  int idx = blockIdx.x*256 + threadIdx.x;
  if (idx < 4096*OUTC){
    int k = idx >> 7, o = idx & 127;
    wlT[idx] = wl[(size_t)o*4096 + k];
  }
}
__global__ __launch_bounds__(256) void k_twf(const float* __restrict__ wf, float* __restrict__ wfT){
  int idx = blockIdx.x*256 + threadIdx.x;
  if (idx < 192*OUTC){
    int k = idx >> 7, o = idx & 127;
    wfT[idx] = wf[o*192 + k];
  }
}

// ---------------- farthest point sampling ----------------
__global__ __launch_bounds__(512) void k_fps(const float* __restrict__ xyz,
                                             int* __restrict__ fidx,
                                             float* __restrict__ nxyz){
  const int b = blockIdx.x;
  const int t = threadIdx.x;
  const float* xb = xyz + (size_t)b*NN*3;
  float px[16], py[16], pz[16], dist[16];
#pragma unroll
  for (int i=0;i<16;i++){
    int id = i*512 + t;
    px[i] = xb[id*3+0]; py[i] = xb[id*3+1]; pz[i] = xb[id*3+2];
    dist[i] = 1e10f;
  }
  __shared__ float redv[8];
  __shared__ int   redi[8];
  __shared__ int   s_last;
  if (t==0){
    fidx[b*MM] = 0;
    nxyz[(size_t)b*MM*3+0]=xb[0]; nxyz[(size_t)b*MM*3+1]=xb[1]; nxyz[(size_t)b*MM*3+2]=xb[2];
  }
  int last = 0;
  for (int step=1; step<MM; ++step){
    const float lx = xb[last*3+0], ly = xb[last*3+1], lz = xb[last*3+2];
    float bv = -1.0f; int bi = 0;
#pragma unroll
    for (int i=0;i<16;i++){
      float dx=px[i]-lx, dy=py[i]-ly, dz=pz[i]-lz;
      float d = dx*dx + dy*dy + dz*dz;
      float nd = fminf(dist[i], d);
      dist[i] = nd;
      if (nd > bv){ bv = nd; bi = i*512 + t; }
    }
#pragma unroll
    for (int off=1; off<64; off<<=1){
      float ov = __shfl_xor(bv, off);
      int   oi = __shfl_xor(bi, off);
      if (ov > bv || (ov == bv && oi < bi)){ bv = ov; bi = oi; }
    }
    if ((t & 63) == 0){ redv[t>>6] = bv; redi[t>>6] = bi; }
    __syncthreads();
    if (t == 0){
      float best = redv[0]; int bid = redi[0];
#pragma unroll
      for (int w=1; w<8; w++){
        if (redv[w] > best || (redv[w]==best && redi[w] < bid)){ best=redv[w]; bid=redi[w]; }
      }
      s_last = bid;
      fidx[b*MM + step] = bid;
      nxyz[((size_t)b*MM+step)*3+0]=xb[bid*3+0];
      nxyz[((size_t)b*MM+step)*3+1]=xb[bid*3+1];
      nxyz[((size_t)b*MM+step)*3+2]=xb[bid*3+2];
    }
    __syncthreads();
    last = s_last;
  }
}

// ---------------- ball query + 3-layer MLP -> per-neighbor weights ----------------
__global__ __launch_bounds__(64) void k_bq_mlp(const float* __restrict__ xyz,
    const float* __restrict__ nxyz,
    const float* __restrict__ w0, const float* __restrict__ b0,
    const float* __restrict__ g0, const float* __restrict__ be0,
    const float* __restrict__ w1, const float* __restrict__ b1,
    const float* __restrict__ g1, const float* __restrict__ be1,
    const float* __restrict__ w2, const float* __restrict__ b2,
    int* __restrict__ gidx, float* __restrict__ wbuf){
  const int bm = blockIdx.x;
  const int b  = bm >> 8;
  const int c  = threadIdx.x;
  __shared__ int   sidx[SS];
  __shared__ float sgx[3][SS];

  const float w0r0 = w0[c*3+0], w0r1 = w0[c*3+1], w0r2 = w0[c*3+2];
  const float b0c=b0[c], g0c=g0[c], be0c=be0[c];
  const float b1c=b1[c], g1c=g1[c], be1c=be1[c], b2c=b2[c];
  float w1r[64], w2r[64];
#pragma unroll
  for (int i=0;i<16;i++){
    float4 v = *(const float4*)(w1 + c*64 + i*4);
    w1r[i*4+0]=v.x; w1r[i*4+1]=v.y; w1r[i*4+2]=v.z; w1r[i*4+3]=v.w;
    float4 u = *(const float4*)(w2 + c*64 + i*4);
    w2r[i*4+0]=u.x; w2r[i*4+1]=u.y; w2r[i*4+2]=u.z; w2r[i*4+3]=u.w;
  }
  const float cx = nxyz[bm*3+0], cy = nxyz[bm*3+1], cz = nxyz[bm*3+2];
  const float* xb = xyz + (size_t)b*NN*3;
  const float R2 = (float)(0.4*0.4);
  int cnt = 0;
  for (int n0=0; n0<NN && cnt<SS; n0+=64){
    int n = n0 + c;
    float dx = xb[n*3+0]-cx, dy = xb[n*3+1]-cy, dz = xb[n*3+2]-cz;
    float d2 = dx*dx+dy*dy+dz*dz;
    bool in = (d2 <= R2);
    unsigned long long mk = __ballot(in);
    int rank = cnt + (int)__popcll(mk & ((1ull<<c)-1ull));
    if (in && rank < SS) sidx[rank] = n;
    cnt += (int)__popcll(mk);
  }
  int total = min(cnt, SS);
  __syncthreads();
  int i0 = sidx[0];
  if (c >= total && c < SS) sidx[c] = i0;
  __syncthreads();
  if (c < SS){
    int p = sidx[c];
    gidx[bm*SS + c] = p;
    sgx[0][c] = xb[p*3+0]-cx;
    sgx[1][c] = xb[p*3+1]-cy;
    sgx[2][c] = xb[p*3+2]-cz;
  }
  __syncthreads();
  float* wb = wbuf + (size_t)bm*SS*WCC;
  for (int s=0;s<SS;s++){
    float x0 = sgx[0][s], x1 = sgx[1][s], x2 = sgx[2][s];
    float pre = w0r0*x0 + w0r1*x1 + w0r2*x2 + b0c;
    float h0 = fmaxf(bnf(pre, g0c, be0c), 0.f);
    float a1 = b1c;
#pragma unroll
    for (int k=0;k<64;k++) a1 += w1r[k]*__shfl(h0, k, 64);
    float h1 = fmaxf(bnf(a1, g1c, be1c), 0.f);
    float a2 = b2c;
#pragma unroll
    for (int k=0;k<64;k++) a2 += w2r[k]*__shfl(h1, k, 64);
    wb[s*WCC + c] = a2;
  }
}

// ---------------- aggregation: agg[bm, d*64+w] = sum_s feat[d,s]*wt[w,s] ----------------
__global__ __launch_bounds__(256) void k_agg(const float* __restrict__ featT,
                                             const float* __restrict__ wbuf,
                                             const int* __restrict__ gidx,
                                             float* __restrict__ agg){
  const int bm = blockIdx.x;
  const int b  = bm >> 8;
  __shared__ float wt[SS][WCC];
  __shared__ int   sidx[SS];
  const int t = threadIdx.x;
  const float* wsrc = wbuf + (size_t)bm*SS*WCC;
#pragma unroll
  for (int i=0;i<8;i++){
    int li = t + i*256;
    ((float*)wt)[li] = wsrc[li];
  }
  if (t < SS) sidx[t] = gidx[bm*SS + t];
  __syncthreads();
  const int d  = t & 63;
  const int wg = t >> 6;
  float acc[16];
#pragma unroll
  for (int j=0;j<16;j++) acc[j]=0.f;
  const float* fb = featT + (size_t)b*NN*DD;
  for (int s=0;s<SS;s++){
    float fv = fb[(size_t)sidx[s]*DD + d];
#pragma unroll
    for (int j=0;j<16;j++) acc[j] += fv * wt[s][wg*16+j];
  }
  float* ab = agg + (size_t)bm*4096 + d*64 + wg*16;
#pragma unroll
  for (int j=0;j<16;j+=4){
    *(float4*)(ab+j) = make_float4(acc[j],acc[j+1],acc[j+2],acc[j+3]);
  }
}

// ---------------- new_feature GEMM: nfT[bm, o] = relu(bn(wl @ agg + bl)) ----------------
__global__ __launch_bounds__(256) void k_nf(const float* __restrict__ agg, const float* __restrict__ wlT,
    const float* __restrict__ bl, const float* __restrict__ gl, const float* __restrict__ bel,
    float* __restrict__ nfT){
  const int row0 = blockIdx.x * 64;
  __shared__ float As[64][65];
  __shared__ float Bs[64][128];
  const int t = threadIdx.x;
  float acc[4][8];
#pragma unroll
  for (int i=0;i<4;i++)
#pragma unroll
    for (int j=0;j<8;j++) acc[i][j]=0.f;
  const int mg = t >> 4, og = t & 15;
  for (int k0=0; k0<4096; k0+=64){
    {
      const int r = t >> 2, c0 = (t & 3) << 4;
      const float* src = agg + (size_t)(row0 + r)*4096 + k0 + c0;
#pragma unroll
      for (int i=0;i<16;i+=4){
        float4 v = *(const float4*)(src+i);
        As[r][c0+i+0]=v.x; As[r][c0+i+1]=v.y; As[r][c0+i+2]=v.z; As[r][c0+i+3]=v.w;
      }
    }
#pragma unroll
    for (int ch=0; ch<8; ch++){
      int li = ch*1024 + t*4;
      int kk = li >> 7, o = li & 127;
      float4 v = *(const float4*)(wlT + (size_t)(k0+kk)*128 + o);
      *(float4*)(&Bs[kk][o]) = v;
    }
    __syncthreads();
#pragma unroll 8
    for (int kk=0; kk<64; kk++){
      float a0 = As[mg*4+0][kk], a1 = As[mg*4+1][kk], a2 = As[mg*4+2][kk], a3 = As[mg*4+3][kk];
      float4 bA = *(float4*)(&Bs[kk][og*8]);
      float4 bB = *(float4*)(&Bs[kk][og*8+4]);
      float bb[8] = {bA.x,bA.y,bA.z,bA.w,bB.x,bB.y,bB.z,bB.w};
#pragma unroll
      for (int j=0;j<8;j++){
        acc[0][j] += a0*bb[j];
        acc[1][j] += a1*bb[j];
        acc[2][j] += a2*bb[j];
        acc[3][j] += a3*bb[j];
      }
    }
    __syncthreads();
  }
#pragma unroll
  for (int i=0;i<4;i++){
    const int row = row0 + mg*4 + i;
    float ov[8];
#pragma unroll
    for (int j=0;j<8;j++){
      const int o = og*8 + j;
      ov[j] = fmaxf(bnf(acc[i][j] + bl[o], gl[o], bel[o]), 0.f);
    }
    float* dst = nfT + (size_t)row*128 + og*8;
    *(float4*)(dst)   = make_float4(ov[0],ov[1],ov[2],ov[3]);
    *(float4*)(dst+4) = make_float4(ov[4],ov[5],ov[6],ov[7]);
  }
}

// ---------------- 3-NN + interpolation -> interpT (B,N,128) ----------------
__global__ __launch_bounds__(256) void k_3nn(const float* __restrict__ xyz, const float* __restrict__ nxyz,
    const float* __restrict__ nfT, float* __restrict__ interpT){
  const int blk = blockIdx.x;
  const int b  = blk >> 5;
  const int n0 = (blk & 31) << 8;
  __shared__ float snew[MM][3];
  __shared__ float sw[256][3];
  __shared__ int   si[256][3];
  const int t = threadIdx.x;
  if (t < 192){
    float4 v = *(const float4*)(nxyz + (size_t)b*MM*3 + t*4);
    ((float*)snew)[t*4+0]=v.x; ((float*)snew)[t*4+1]=v.y; ((float*)snew)[t*4+2]=v.z; ((float*)snew)[t*4+3]=v.w;
  }
  __syncthreads();
  {
    const int n = n0 + t;
    const float x = xyz[((size_t)b*NN+n)*3+0];
    const float y = xyz[((size_t)b*NN+n)*3+1];
    const float z = xyz[((size_t)b*NN+n)*3+2];
    float d1=1e30f, d2=1e30f, d3=1e30f; int i1=0,i2=0,i3=0;
    for (int m=0;m<MM;m++){
      float dx=x-snew[m][0], dy=y-snew[m][1], dz=z-snew[m][2];
      float d = dx*dx+dy*dy+dz*dz;
      if (d < d3){
        if (d < d1){ d3=d2;i3=i2; d2=d1;i2=i1; d1=d;i1=m; }
        else if (d < d2){ d3=d2;i3=i2; d2=d;i2=m; }
        else { d3=d;i3=m; }
      }
    }
    float r1=1.f/(d1+1e-8f), r2=1.f/(d2+1e-8f), r3=1.f/(d3+1e-8f);
    float rs = 1.f/(r1+r2+r3);
    sw[t][0]=r1*rs; sw[t][1]=r2*rs; sw[t][2]=r3*rs;
    si[t][0]=i1; si[t][1]=i2; si[t][2]=i3;
  }
  __syncthreads();
  const int c = t & 127, half = t >> 7;
  for (int r=0;r<128;r++){
    const int nn = r*2 + half;
    const float w0v=sw[nn][0], w1v=sw[nn][1], w2v=sw[nn][2];
    const float* p0 = nfT + ((size_t)b*MM + si[nn][0])*128;
    const float* p1 = nfT + ((size_t)b*MM + si[nn][1])*128;
    const float* p2 = nfT + ((size_t)b*MM + si[nn][2])*128;
    interpT[((size_t)b*NN + n0 + nn)*128 + c] = w0v*p0[c] + w1v*p1[c] + w2v*p2[c];
  }
}

// ---------------- final conv: out[b,o,n] = relu(bn(wf @ [interp;feature] + bf)) ----------------
__global__ __launch_bounds__(256) void k_final(const float* __restrict__ interpT, const float* __restrict__ feature,
    const float* __restrict__ wfT,
    const float* __restrict__ bf, const float* __restrict__ gf, const float* __restrict__ bef,
    float* __restrict__ out){
  const int blk = blockIdx.x;
  const int b  = blk >> 6;
  const int n0 = (blk & 63) << 7;
  __shared__ float Wsh[32][128];
  __shared__ float Csh[32][132];
  const int t = threadIdx.x;
  float acc[8][8];
#pragma unroll
  for (int i=0;i<8;i++)
#pragma unroll
    for (int j=0;j<8;j++) acc[i][j]=0.f;
  const int og = t >> 4, ng = t & 15;
  for (int k0=0; k0<192; k0+=32){
    {
      const int kk = t >> 3, o0 = (t & 7) << 4;
#pragma unroll
      for (int i=0;i<16;i+=4)
        *(float4*)(&Wsh[kk][o0+i]) = *(const float4*)(wfT + (size_t)(k0+kk)*128 + o0 + i);
    }
    if (k0 < 128){
      const int nn = t >> 1, kb = (t & 1) << 4;
      const float* src = interpT + ((size_t)b*NN + n0 + nn)*128 + k0 + kb;
#pragma unroll
      for (int i=0;i<16;i+=4){
        float4 v = *(const float4*)(src+i);
        Csh[kb+i+0][nn]=v.x; Csh[kb+i+1][nn]=v.y; Csh[kb+i+2][nn]=v.z; Csh[kb+i+3][nn]=v.w;
      }
    } else {
      const int kk = t >> 3, nb = (t & 7) << 4;
      const float* src = feature + ((size_t)b*DD + (k0-128) + kk)*NN + n0 + nb;
#pragma unroll
      for (int i=0;i<16;i+=4){
        float4 v = *(const float4*)(src+i);
        *(float4*)(&Csh[kk][nb+i]) = v;
      }
    }
    __syncthreads();
#pragma unroll 8
    for (int kk=0;kk<32;kk++){
      float4 a0 = *(float4*)(&Wsh[kk][og*8]);
      float4 a1 = *(float4*)(&Wsh[kk][og*8+4]);
      float av[8] = {a0.x,a0.y,a0.z,a0.w,a1.x,a1.y,a1.z,a1.w};
      float4 c0 = *(float4*)(&Csh[kk][ng*8]);
      float4 c1 = *(float4*)(&Csh[kk][ng*8+4]);
      float cv[8] = {c0.x,c0.y,c0.z,c0.w,c1.x,c1.y,c1.z,c1.w};
#pragma unroll
      for (int i=0;i<8;i++)
#pragma unroll
        for (int j=0;j<8;j++)
          acc[i][j] += av[i]*cv[j];
    }
    __syncthreads();
  }
#pragma unroll
  for (int i=0;i<8;i++){
    const int o = og*8 + i;
    const float bfo = bf[o], gfo = gf[o], befo = bef[o];
    float ov[8];
#pragma unroll
    for (int j=0;j<8;j++) ov[j] = fmaxf(bnf(acc[i][j] + bfo, gfo, befo), 0.f);
    float* dst = out + ((size_t)b*OUTC + o)*NN + n0 + ng*8;
    *(float4*)(dst)   = make_float4(ov[0],ov[1],ov[2],ov[3]);
    *(float4*)(dst+4) = make_float4(ov[4],ov[5],ov[6],ov[7]);
  }
}

extern "C" void kernel_launch(void* const* d_in, const int* in_sizes, int n_in,
                              void* d_out, int out_size, void* d_ws, size_t ws_size,
                              hipStream_t stream){
  const float* xyz     = (const float*)d_in[0];
  const float* feature = (const float*)d_in[1];
  const float* w0  = (const float*)d_in[2];
  const float* b0  = (const float*)d_in[3];
  const float* g0  = (const float*)d_in[4];
  const float* be0 = (const float*)d_in[5];
  const float* w1  = (const float*)d_in[6];
  const float* b1  = (const float*)d_in[7];
  const float* g1  = (const float*)d_in[8];
  const float* be1 = (const float*)d_in[9];
  const float* w2  = (const float*)d_in[10];
  const float* b2  = (const float*)d_in[11];
  const float* wl  = (const float*)d_in[12];
  const float* bl  = (const float*)d_in[13];
  const float* gl  = (const float*)d_in[14];
  const float* bel = (const float*)d_in[15];
  const float* wf  = (const float*)d_in[16];
  const float* bf  = (const float*)d_in[17];
  const float* gf  = (const float*)d_in[18];
  const float* bef = (const float*)d_in[19];
  float* out = (float*)d_out;

  char* ws = (char*)d_ws;
  float* featT = (float*)(ws + 0);          // 33,554,432 B
  float* wbuf  = (float*)(ws + 33554432);   // 33,554,432 B
  float* agg   = (float*)(ws + 67108864);   // 67,108,864 B
  float* wlT   = (float*)(ws + 134217728);  //  2,097,152 B
  float* wfT   = (float*)(ws + 136314880);  //     98,304 B
  int*   fidx  = (int*)  (ws + 136413184);  //     16,384 B
  float* nxyz  = (float*)(ws + 136429568);  //     49,152 B
  int*   gidx  = (int*)  (ws + 136478720);  //    524,288 B
  float* nfT   = (float*)(ws + 137003008);  //  2,097,152 B  (end 139,100,160)
  float* interpT = (float*)(ws + 0);        // aliases featT+wbuf (both dead by then)

  k_tf    <<<2048, 256, 0, stream>>>(feature, featT);
  k_twl   <<<2048, 256, 0, stream>>>(wl, wlT);
  k_twf   <<<96,   256, 0, stream>>>(wf, wfT);
  k_fps   <<<BB,   512, 0, stream>>>(xyz, fidx, nxyz);
  k_bq_mlp<<<BB*MM, 64, 0, stream>>>(xyz, nxyz, w0,b0,g0,be0, w1,b1,g1,be1, w2,b2, gidx, wbuf);
  k_agg   <<<BB*MM, 256, 0, stream>>>(featT, wbuf, gidx, agg);
  k_nf    <<<64,   256, 0, stream>>>(agg, wlT, bl, gl, bel, nfT);
  k_3nn   <<<BB*(NN/256), 256, 0, stream>>>(xyz, nxyz, nfT, interpT);
  k_final <<<BB*(NN/128), 256, 0, stream>>>(interpT, feature, wfT, bf, gf, bef, out);
}

// Round 2
// 916.056 us; speedup vs baseline: 1.2985x; 1.2985x over previous
//
#include <hip/hip_runtime.h>
#include <cstdint>
#include <cstddef>

#define BB   16
#define NN   8192
#define DD   64
#define MM   256
#define SS   32
#define OUTC 128
#define WCC  64

__device__ __forceinline__ float bnf(float x, float g, float be){
    const float BNS = 0.99999500003749969f; // 1/sqrt(1+1e-5)
    return g * (x * BNS) + be;
}

// ---------------- feature transpose (B,D,N) -> (B,N,D) ----------------
__global__ __launch_bounds__(256) void k_tf(const float* __restrict__ f, float* __restrict__ fT){
  const int blk = blockIdx.x;
  const int b  = blk >> 7;
  const int n0 = (blk & 127) << 6;
  __shared__ float tile[64][65];
  const int t = threadIdx.x;
  {
    const int d = t >> 2, j0 = (t & 3) << 4;
    const float* src = f + ((size_t)b*DD + d)*NN + n0 + j0;
#pragma unroll
    for (int i=0;i<16;i+=4){
      float4 v = *(const float4*)(src + i);
      tile[d][j0+i+0]=v.x; tile[d][j0+i+1]=v.y; tile[d][j0+i+2]=v.z; tile[d][j0+i+3]=v.w;
    }
  }
  __syncthreads();
  {
    const int j = t >> 2, d0 = (t & 3) << 4;
    float* dst = fT + ((size_t)b*NN + n0 + j)*DD + d0;
#pragma unroll
    for (int i=0;i<16;i+=4){
      float4 v = make_float4(tile[d0+i][j], tile[d0+i+1][j], tile[d0+i+2][j], tile[d0+i+3][j]);
      *(float4*)(dst + i) = v;
    }
  }
}

// ---------------- small weight transposes ----------------
__global__ __launch_bounds__(256) void k_twl(const float* __restrict__ wl, float* __restrict__ wlT){
  int idx = blockIdx.x*256 + threadIdx.x;
  if (idx < 4096*OUTC){
    int k = idx >> 7, o = idx & 127;
    wlT[idx] = wl[(size_t)o*4096 + k];
  }
}
__global__ __launch_bounds__(256) void k_twf(const float* __restrict__ wf, float* __restrict__ wfT){
  int idx = blockIdx.x*256 + threadIdx.x;
  if (idx < 192*OUTC){
    int k = idx >> 7, o = idx & 127;
    wfT[idx] = wf[o*192 + k];
  }
}

// ---------------- farthest point sampling (LDS-resident, 1 barrier/step) ----------------
__global__ __launch_bounds__(512) void k_fps(const float* __restrict__ xyz,
                                             float* __restrict__ nxyz){
  const int b = blockIdx.x;
  const int t = threadIdx.x;
  const float* xb = xyz + (size_t)b*NN*3;
  __shared__ float sxyz[NN*3];   // 96 KB: whole cloud in LDS
  __shared__ float snew[MM*3];   // 3 KB: selected centroids
  __shared__ float redv[2][8];
  __shared__ int   redi[2][8];
  for (int i = t; i < NN*3; i += 512) sxyz[i] = xb[i];
  float px[16], py[16], pz[16], dist[16];
#pragma unroll
  for (int i=0;i<16;i++){
    int id = i*512 + t;
    px[i] = xb[id*3+0]; py[i] = xb[id*3+1]; pz[i] = xb[id*3+2];
    dist[i] = 1e10f;
  }
  __syncthreads();
  float lx = sxyz[0], ly = sxyz[1], lz = sxyz[2];
  if (t==0){ snew[0]=lx; snew[1]=ly; snew[2]=lz; }
  for (int step=1; step<MM; ++step){
    float bv = -1.0f; int bi = 0;
#pragma unroll
    for (int i=0;i<16;i++){
      float dx=px[i]-lx, dy=py[i]-ly, dz=pz[i]-lz;
      float d = dx*dx + dy*dy + dz*dz;
      float nd = fminf(dist[i], d);
      dist[i] = nd;
      bool gt = nd > bv;
      bv = gt ? nd : bv;
      bi = gt ? (i*512 + t) : bi;
    }
#pragma unroll
    for (int off=1; off<64; off<<=1){
      float ov = __shfl_xor(bv, off);
      int   oi = __shfl_xor(bi, off);
      if (ov > bv || (ov == bv && oi < bi)){ bv = ov; bi = oi; }
    }
    const int p = step & 1;
    if ((t & 63) == 0){ redv[p][t>>6] = bv; redi[p][t>>6] = bi; }
    __syncthreads();   // single barrier per step (double-buffered redv/redi)
    float best = redv[p][0]; int bid = redi[p][0];
#pragma unroll
    for (int w=1; w<8; w++){
      float v = redv[p][w]; int ii = redi[p][w];
      if (v > best || (v == best && ii < bid)){ best = v; bid = ii; }
    }
    lx = sxyz[bid*3+0]; ly = sxyz[bid*3+1]; lz = sxyz[bid*3+2];
    if (t==0){ snew[step*3+0]=lx; snew[step*3+1]=ly; snew[step*3+2]=lz; }
  }
  __syncthreads();
  for (int i = t; i < MM*3; i += 512) nxyz[(size_t)b*MM*3 + i] = snew[i];
}

// ---------------- ball query + 3-layer MLP -> per-neighbor weights ----------------
__global__ __launch_bounds__(64) void k_bq_mlp(const float* __restrict__ xyz,
    const float* __restrict__ nxyz,
    const float* __restrict__ w0, const float* __restrict__ b0,
    const float* __restrict__ g0, const float* __restrict__ be0,
    const float* __restrict__ w1, const float* __restrict__ b1,
    const float* __restrict__ g1, const float* __restrict__ be1,
    const float* __restrict__ w2, const float* __restrict__ b2,
    int* __restrict__ gidx, float* __restrict__ wbuf){
  const int bm = blockIdx.x;
  const int b  = bm >> 8;
  const int c  = threadIdx.x;
  __shared__ int   sidx[SS];
  __shared__ float sgx[3][SS];

  const float w0r0 = w0[c*3+0], w0r1 = w0[c*3+1], w0r2 = w0[c*3+2];
  const float b0c=b0[c], g0c=g0[c], be0c=be0[c];
  const float b1c=b1[c], g1c=g1[c], be1c=be1[c], b2c=b2[c];
  float w1r[64], w2r[64];
#pragma unroll
  for (int i=0;i<16;i++){
    float4 v = *(const float4*)(w1 + c*64 + i*4);
    w1r[i*4+0]=v.x; w1r[i*4+1]=v.y; w1r[i*4+2]=v.z; w1r[i*4+3]=v.w;
    float4 u = *(const float4*)(w2 + c*64 + i*4);
    w2r[i*4+0]=u.x; w2r[i*4+1]=u.y; w2r[i*4+2]=u.z; w2r[i*4+3]=u.w;
  }
  const float cx = nxyz[bm*3+0], cy = nxyz[bm*3+1], cz = nxyz[bm*3+2];
  const float* xb = xyz + (size_t)b*NN*3;
  const float R2 = (float)(0.4*0.4);
  int cnt = 0;
  for (int n0=0; n0<NN && cnt<SS; n0+=64){
    int n = n0 + c;
    float dx = xb[n*3+0]-cx, dy = xb[n*3+1]-cy, dz = xb[n*3+2]-cz;
    float d2 = dx*dx+dy*dy+dz*dz;
    bool in = (d2 <= R2);
    unsigned long long mk = __ballot(in);
    int rank = cnt + (int)__popcll(mk & ((1ull<<c)-1ull));
    if (in && rank < SS) sidx[rank] = n;
    cnt += (int)__popcll(mk);
  }
  int total = min(cnt, SS);
  __syncthreads();
  int i0 = sidx[0];
  if (c >= total && c < SS) sidx[c] = i0;
  __syncthreads();
  if (c < SS){
    int p = sidx[c];
    gidx[bm*SS + c] = p;
    sgx[0][c] = xb[p*3+0]-cx;
    sgx[1][c] = xb[p*3+1]-cy;
    sgx[2][c] = xb[p*3+2]-cz;
  }
  __syncthreads();
  float* wb = wbuf + (size_t)bm*SS*WCC;
  for (int s=0;s<SS;s++){
    float x0 = sgx[0][s], x1 = sgx[1][s], x2 = sgx[2][s];
    float pre = w0r0*x0 + w0r1*x1 + w0r2*x2 + b0c;
    float h0 = fmaxf(bnf(pre, g0c, be0c), 0.f);
    float a1 = b1c;
#pragma unroll
    for (int k=0;k<64;k++) a1 += w1r[k]*__shfl(h0, k, 64);
    float h1 = fmaxf(bnf(a1, g1c, be1c), 0.f);
    float a2 = b2c;
#pragma unroll
    for (int k=0;k<64;k++) a2 += w2r[k]*__shfl(h1, k, 64);
    wb[s*WCC + c] = a2;
  }
}

// ---------------- aggregation: agg[bm, d*64+w] = sum_s feat[d,s]*wt[w,s] ----------------
__global__ __launch_bounds__(256) void k_agg(const float* __restrict__ featT,
                                             const float* __restrict__ wbuf,
                                             const int* __restrict__ gidx,
                                             float* __restrict__ agg){
  const int bm = blockIdx.x;
  const int b  = bm >> 8;
  __shared__ float wt[SS][WCC];
  __shared__ int   sidx[SS];
  const int t = threadIdx.x;
  const float* wsrc = wbuf + (size_t)bm*SS*WCC;
#pragma unroll
  for (int i=0;i<8;i++){
    int li = t + i*256;
    ((float*)wt)[li] = wsrc[li];
  }
  if (t < SS) sidx[t] = gidx[bm*SS + t];
  __syncthreads();
  const int d  = t & 63;
  const int wg = t >> 6;
  float acc[16];
#pragma unroll
  for (int j=0;j<16;j++) acc[j]=0.f;
  const float* fb = featT + (size_t)b*NN*DD;
  for (int s=0;s<SS;s++){
    float fv = fb[(size_t)sidx[s]*DD + d];
#pragma unroll
    for (int j=0;j<16;j++) acc[j] += fv * wt[s][wg*16+j];
  }
  float* ab = agg + (size_t)bm*4096 + d*64 + wg*16;
#pragma unroll
  for (int j=0;j<16;j+=4){
    *(float4*)(ab+j) = make_float4(acc[j],acc[j+1],acc[j+2],acc[j+3]);
  }
}

// ---------------- new_feature GEMM, split-K partial: part[ks][row][o] ----------------
__global__ __launch_bounds__(256) void k_nf_part(const float* __restrict__ agg, const float* __restrict__ wlT,
    float* __restrict__ part){
  const int blk = blockIdx.x;
  const int rb  = blk >> 2;          // 64 row-blocks
  const int ks  = blk & 3;           // 4 K-slices
  const int row0 = rb * 64;
  const int kbase = ks * 1024;
  __shared__ float As[64][65];
  __shared__ float Bs[64][128];
  const int t = threadIdx.x;
  float acc[4][8];
#pragma unroll
  for (int i=0;i<4;i++)
#pragma unroll
    for (int j=0;j<8;j++) acc[i][j]=0.f;
  const int mg = t >> 4, og = t & 15;
  for (int k0=kbase; k0<kbase+1024; k0+=64){
    {
      const int r = t >> 2, c0 = (t & 3) << 4;
      const float* src = agg + (size_t)(row0 + r)*4096 + k0 + c0;
#pragma unroll
      for (int i=0;i<16;i+=4){
        float4 v = *(const float4*)(src+i);
        As[r][c0+i+0]=v.x; As[r][c0+i+1]=v.y; As[r][c0+i+2]=v.z; As[r][c0+i+3]=v.w;
      }
    }
#pragma unroll
    for (int ch=0; ch<8; ch++){
      int li = ch*1024 + t*4;
      int kk = li >> 7, o = li & 127;
      float4 v = *(const float4*)(wlT + (size_t)(k0+kk)*128 + o);
      *(float4*)(&Bs[kk][o]) = v;
    }
    __syncthreads();
#pragma unroll 8
    for (int kk=0; kk<64; kk++){
      float a0 = As[mg*4+0][kk], a1 = As[mg*4+1][kk], a2 = As[mg*4+2][kk], a3 = As[mg*4+3][kk];
      float4 bA = *(float4*)(&Bs[kk][og*8]);
      float4 bB = *(float4*)(&Bs[kk][og*8+4]);
      float bb[8] = {bA.x,bA.y,bA.z,bA.w,bB.x,bB.y,bB.z,bB.w};
#pragma unroll
      for (int j=0;j<8;j++){
        acc[0][j] += a0*bb[j];
        acc[1][j] += a1*bb[j];
        acc[2][j] += a2*bb[j];
        acc[3][j] += a3*bb[j];
      }
    }
    __syncthreads();
  }
  float* pb = part + ((size_t)ks << 19);   // 4096*128 per slice
#pragma unroll
  for (int i=0;i<4;i++){
    const int row = row0 + mg*4 + i;
    float* dst = pb + (size_t)row*128 + og*8;
    *(float4*)(dst)   = make_float4(acc[i][0],acc[i][1],acc[i][2],acc[i][3]);
    *(float4*)(dst+4) = make_float4(acc[i][4],acc[i][5],acc[i][6],acc[i][7]);
  }
}

// ---------------- nf epilogue: sum 4 partials + bias + bn + relu ----------------
__global__ __launch_bounds__(256) void k_nf_ep(const float* __restrict__ part,
    const float* __restrict__ bl, const float* __restrict__ gl, const float* __restrict__ bel,
    float* __restrict__ nfT){
  const int gid = blockIdx.x*256 + threadIdx.x;
  const int base = gid*4;
  const int o0 = base & 127;
  float4 s0 = *(const float4*)(part + base);
  float4 s1 = *(const float4*)(part + (1<<19) + base);
  float4 s2 = *(const float4*)(part + (2<<19) + base);
  float4 s3 = *(const float4*)(part + (3<<19) + base);
  float sum[4] = {s0.x+s1.x+s2.x+s3.x, s0.y+s1.y+s2.y+s3.y,
                  s0.z+s1.z+s2.z+s3.z, s0.w+s1.w+s2.w+s3.w};
  float ov[4];
#pragma unroll
  for (int j=0;j<4;j++){
    const int o = o0 + j;
    ov[j] = fmaxf(bnf(sum[j] + bl[o], gl[o], bel[o]), 0.f);
  }
  *(float4*)(nfT + base) = make_float4(ov[0],ov[1],ov[2],ov[3]);
}

// ---------------- 3-NN + interpolation -> interpT (B,N,128) ----------------
__global__ __launch_bounds__(256) void k_3nn(const float* __restrict__ xyz, const float* __restrict__ nxyz,
    const float* __restrict__ nfT, float* __restrict__ interpT){
  const int blk = blockIdx.x;
  const int b  = blk >> 5;
  const int n0 = (blk & 31) << 8;
  __shared__ float snew[MM][3];
  __shared__ float sw[256][3];
  __shared__ int   si[256][3];
  const int t = threadIdx.x;
  if (t < 192){
    float4 v = *(const float4*)(nxyz + (size_t)b*MM*3 + t*4);
    ((float*)snew)[t*4+0]=v.x; ((float*)snew)[t*4+1]=v.y; ((float*)snew)[t*4+2]=v.z; ((float*)snew)[t*4+3]=v.w;
  }
  __syncthreads();
  {
    const int n = n0 + t;
    const float x = xyz[((size_t)b*NN+n)*3+0];
    const float y = xyz[((size_t)b*NN+n)*3+1];
    const float z = xyz[((size_t)b*NN+n)*3+2];
    float d1=1e30f, d2=1e30f, d3=1e30f; int i1=0,i2=0,i3=0;
    for (int m=0;m<MM;m++){
      float dx=x-snew[m][0], dy=y-snew[m][1], dz=z-snew[m][2];
      float d = dx*dx+dy*dy+dz*dz;
      if (d < d3){
        if (d < d1){ d3=d2;i3=i2; d2=d1;i2=i1; d1=d;i1=m; }
        else if (d < d2){ d3=d2;i3=i2; d2=d;i2=m; }
        else { d3=d;i3=m; }
      }
    }
    float r1=1.f/(d1+1e-8f), r2=1.f/(d2+1e-8f), r3=1.f/(d3+1e-8f);
    float rs = 1.f/(r1+r2+r3);
    sw[t][0]=r1*rs; sw[t][1]=r2*rs; sw[t][2]=r3*rs;
    si[t][0]=i1; si[t][1]=i2; si[t][2]=i3;
  }
  __syncthreads();
  const int c = t & 127, half = t >> 7;
  for (int r=0;r<128;r++){
    const int nn = r*2 + half;
    const float w0v=sw[nn][0], w1v=sw[nn][1], w2v=sw[nn][2];
    const float* p0 = nfT + ((size_t)b*MM + si[nn][0])*128;
    const float* p1 = nfT + ((size_t)b*MM + si[nn][1])*128;
    const float* p2 = nfT + ((size_t)b*MM + si[nn][2])*128;
    interpT[((size_t)b*NN + n0 + nn)*128 + c] = w0v*p0[c] + w1v*p1[c] + w2v*p2[c];
  }
}

// ---------------- final conv: out[b,o,n] = relu(bn(wf @ [interp;feature] + bf)) ----------------
__global__ __launch_bounds__(256) void k_final(const float* __restrict__ interpT, const float* __restrict__ feature,
    const float* __restrict__ wfT,
    const float* __restrict__ bf, const float* __restrict__ gf, const float* __restrict__ bef,
    float* __restrict__ out){
  const int blk = blockIdx.x;
  const int b  = blk >> 6;
  const int n0 = (blk & 63) << 7;
  __shared__ float Wsh[32][128];
  __shared__ float Csh[32][132];
  const int t = threadIdx.x;
  float acc[8][8];
#pragma unroll
  for (int i=0;i<8;i++)
#pragma unroll
    for (int j=0;j<8;j++) acc[i][j]=0.f;
  const int og = t >> 4, ng = t & 15;
  for (int k0=0; k0<192; k0+=32){
    {
      const int kk = t >> 3, o0 = (t & 7) << 4;
#pragma unroll
      for (int i=0;i<16;i+=4)
        *(float4*)(&Wsh[kk][o0+i]) = *(const float4*)(wfT + (size_t)(k0+kk)*128 + o0 + i);
    }
    if (k0 < 128){
      const int nn = t >> 1, kb = (t & 1) << 4;
      const float* src = interpT + ((size_t)b*NN + n0 + nn)*128 + k0 + kb;
#pragma unroll
      for (int i=0;i<16;i+=4){
        float4 v = *(const float4*)(src+i);
        Csh[kb+i+0][nn]=v.x; Csh[kb+i+1][nn]=v.y; Csh[kb+i+2][nn]=v.z; Csh[kb+i+3][nn]=v.w;
      }
    } else {
      const int kk = t >> 3, nb = (t & 7) << 4;
      const float* src = feature + ((size_t)b*DD + (k0-128) + kk)*NN + n0 + nb;
#pragma unroll
      for (int i=0;i<16;i+=4){
        float4 v = *(const float4*)(src+i);
        *(float4*)(&Csh[kk][nb+i]) = v;
      }
    }
    __syncthreads();
#pragma unroll 8
    for (int kk=0;kk<32;kk++){
      float4 a0 = *(float4*)(&Wsh[kk][og*8]);
      float4 a1 = *(float4*)(&Wsh[kk][og*8+4]);
      float av[8] = {a0.x,a0.y,a0.z,a0.w,a1.x,a1.y,a1.z,a1.w};
      float4 c0 = *(float4*)(&Csh[kk][ng*8]);
      float4 c1 = *(float4*)(&Csh[kk][ng*8+4]);
      float cv[8] = {c0.x,c0.y,c0.z,c0.w,c1.x,c1.y,c1.z,c1.w};
#pragma unroll
      for (int i=0;i<8;i++)
#pragma unroll
        for (int j=0;j<8;j++)
          acc[i][j] += av[i]*cv[j];
    }
    __syncthreads();
  }
#pragma unroll
  for (int i=0;i<8;i++){
    const int o = og*8 + i;
    const float bfo = bf[o], gfo = gf[o], befo = bef[o];
    float ov[8];
#pragma unroll
    for (int j=0;j<8;j++) ov[j] = fmaxf(bnf(acc[i][j] + bfo, gfo, befo), 0.f);
    float* dst = out + ((size_t)b*OUTC + o)*NN + n0 + ng*8;
    *(float4*)(dst)   = make_float4(ov[0],ov[1],ov[2],ov[3]);
    *(float4*)(dst+4) = make_float4(ov[4],ov[5],ov[6],ov[7]);
  }
}

extern "C" void kernel_launch(void* const* d_in, const int* in_sizes, int n_in,
                              void* d_out, int out_size, void* d_ws, size_t ws_size,
                              hipStream_t stream){
  const float* xyz     = (const float*)d_in[0];
  const float* feature = (const float*)d_in[1];
  const float* w0  = (const float*)d_in[2];
  const float* b0  = (const float*)d_in[3];
  const float* g0  = (const float*)d_in[4];
  const float* be0 = (const float*)d_in[5];
  const float* w1  = (const float*)d_in[6];
  const float* b1  = (const float*)d_in[7];
  const float* g1  = (const float*)d_in[8];
  const float* be1 = (const float*)d_in[9];
  const float* w2  = (const float*)d_in[10];
  const float* b2  = (const float*)d_in[11];
  const float* wl  = (const float*)d_in[12];
  const float* bl  = (const float*)d_in[13];
  const float* gl  = (const float*)d_in[14];
  const float* bel = (const float*)d_in[15];
  const float* wf  = (const float*)d_in[16];
  const float* bf  = (const float*)d_in[17];
  const float* gf  = (const float*)d_in[18];
  const float* bef = (const float*)d_in[19];
  float* out = (float*)d_out;

  char* ws = (char*)d_ws;
  float* featT = (float*)(ws + 0);          // 33,554,432 B
  float* wbuf  = (float*)(ws + 33554432);   // 33,554,432 B (dead after k_agg)
  float* part  = (float*)(ws + 33554432);   // 8 MB, reuses wbuf region after k_agg
  float* agg   = (float*)(ws + 67108864);   // 67,108,864 B
  float* wlT   = (float*)(ws + 134217728);  //  2,097,152 B
  float* wfT   = (float*)(ws + 136314880);  //     98,304 B
  float* nxyz  = (float*)(ws + 136429568);  //     49,152 B
  int*   gidx  = (int*)  (ws + 136478720);  //    524,288 B
  float* nfT   = (float*)(ws + 137003008);  //  2,097,152 B
  float* interpT = (float*)(ws + 0);        // 67 MB, aliases featT+wbuf/part (dead by then)

  k_tf     <<<2048, 256, 0, stream>>>(feature, featT);
  k_twl    <<<2048, 256, 0, stream>>>(wl, wlT);
  k_twf    <<<96,   256, 0, stream>>>(wf, wfT);
  k_fps    <<<BB,   512, 0, stream>>>(xyz, nxyz);
  k_bq_mlp <<<BB*MM, 64, 0, stream>>>(xyz, nxyz, w0,b0,g0,be0, w1,b1,g1,be1, w2,b2, gidx, wbuf);
  k_agg    <<<BB*MM, 256, 0, stream>>>(featT, wbuf, gidx, agg);
  k_nf_part<<<256,  256, 0, stream>>>(agg, wlT, part);
  k_nf_ep  <<<512,  256, 0, stream>>>(part, bl, gl, bel, nfT);
  k_3nn    <<<BB*(NN/256), 256, 0, stream>>>(xyz, nxyz, nfT, interpT);
  k_final  <<<BB*(NN/128), 256, 0, stream>>>(interpT, feature, wfT, bf, gf, bef, out);
}

// Round 3
// 642.135 us; speedup vs baseline: 1.8524x; 1.4266x over previous
//
#include <hip/hip_runtime.h>
#include <cstdint>
#include <cstddef>

#define BB   16
#define NN   8192
#define DD   64
#define MM   256
#define SS   32
#define OUTC 128
#define WCC  64

__device__ __forceinline__ float bnf(float x, float g, float be){
    const float BNS = 0.99999500003749969f; // 1/sqrt(1+1e-5)
    return g * (x * BNS) + be;
}

// ---------------- feature transpose (B,D,N) -> (B,N,D) ----------------
__global__ __launch_bounds__(256) void k_tf(const float* __restrict__ f, float* __restrict__ fT){
  const int blk = blockIdx.x;
  const int b  = blk >> 7;
  const int n0 = (blk & 127) << 6;
  __shared__ float tile[64][65];
  const int t = threadIdx.x;
  {
    const int d = t >> 2, j0 = (t & 3) << 4;
    const float* src = f + ((size_t)b*DD + d)*NN + n0 + j0;
#pragma unroll
    for (int i=0;i<16;i+=4){
      float4 v = *(const float4*)(src + i);
      tile[d][j0+i+0]=v.x; tile[d][j0+i+1]=v.y; tile[d][j0+i+2]=v.z; tile[d][j0+i+3]=v.w;
    }
  }
  __syncthreads();
  {
    const int j = t >> 2, d0 = (t & 3) << 4;
    float* dst = fT + ((size_t)b*NN + n0 + j)*DD + d0;
#pragma unroll
    for (int i=0;i<16;i+=4){
      float4 v = make_float4(tile[d0+i][j], tile[d0+i+1][j], tile[d0+i+2][j], tile[d0+i+3][j]);
      *(float4*)(dst + i) = v;
    }
  }
}

// ---------------- small weight transposes ----------------
__global__ __launch_bounds__(256) void k_twl(const float* __restrict__ wl, float* __restrict__ wlT){
  int idx = blockIdx.x*256 + threadIdx.x;
  if (idx < 4096*OUTC){
    int k = idx >> 7, o = idx & 127;
    wlT[idx] = wl[(size_t)o*4096 + k];
  }
}
__global__ __launch_bounds__(256) void k_twf(const float* __restrict__ wf, float* __restrict__ wfT){
  int idx = blockIdx.x*256 + threadIdx.x;
  if (idx < 192*OUTC){
    int k = idx >> 7, o = idx & 127;
    wfT[idx] = wf[o*192 + k];
  }
}

// ---------------- farthest point sampling (packed-u64 argmax, 1 barrier/step) ----------------
__global__ __launch_bounds__(256) void k_fps(const float* __restrict__ xyz,
                                             float* __restrict__ nxyz){
  const int b = blockIdx.x;
  const int t = threadIdx.x;
  const float* xb = xyz + (size_t)b*NN*3;
  __shared__ float sxyz[NN*3];   // 96 KB: whole cloud in LDS
  __shared__ float snew[MM*3];   // 3 KB
  __shared__ unsigned long long skey[2][4];
  for (int i = t; i < NN*3; i += 256) sxyz[i] = xb[i];
  float px[32], py[32], pz[32], dist[32];
#pragma unroll
  for (int i=0;i<32;i++){
    int id = i*256 + t;
    px[i] = xb[id*3+0]; py[i] = xb[id*3+1]; pz[i] = xb[id*3+2];
    dist[i] = 1e10f;
  }
  __syncthreads();
  float lx = sxyz[0], ly = sxyz[1], lz = sxyz[2];
  if (t==0){ snew[0]=lx; snew[1]=ly; snew[2]=lz; }
  for (int step=1; step<MM; ++step){
    float bv = 0.0f; int bi = NN-1;
#pragma unroll
    for (int i=0;i<32;i++){
      float dx=px[i]-lx, dy=py[i]-ly, dz=pz[i]-lz;
      float d = dx*dx + dy*dy + dz*dz;
      float nd = fminf(dist[i], d);
      dist[i] = nd;
      bool gt = nd > bv;
      bv = gt ? nd : bv;
      bi = gt ? (i*256 + t) : bi;
    }
    // pack: high 32 = f32 bits (non-negative -> order-monotone), low 32 = 8191-idx (smaller idx wins ties)
    unsigned long long key = ((unsigned long long)__float_as_uint(bv) << 32) | (unsigned)(NN-1 - bi);
#pragma unroll
    for (int off=1; off<64; off<<=1){
      unsigned long long ok = __shfl_xor(key, off, 64);
      if (ok > key) key = ok;
    }
    const int p = step & 1;
    if ((t & 63) == 0) skey[p][t>>6] = key;
    __syncthreads();   // single barrier per step
    unsigned long long k0=skey[p][0], k1=skey[p][1], k2=skey[p][2], k3=skey[p][3];
    unsigned long long ka = k0>k1?k0:k1, kb = k2>k3?k2:k3;
    unsigned long long kw = ka>kb?ka:kb;
    const int bid = (NN-1) - (int)(unsigned)(kw & 0xFFFFFFFFull);
    lx = sxyz[bid*3+0]; ly = sxyz[bid*3+1]; lz = sxyz[bid*3+2];
    if (t==0){ snew[step*3+0]=lx; snew[step*3+1]=ly; snew[step*3+2]=lz; }
  }
  __syncthreads();
  for (int i = t; i < MM*3; i += 256) nxyz[(size_t)b*MM*3 + i] = snew[i];
}

// ---------------- ball query + 3-layer MLP (LDS-staged, no shfl) ----------------
__global__ __launch_bounds__(64) void k_bq_mlp(const float* __restrict__ xyz,
    const float* __restrict__ nxyz,
    const float* __restrict__ w0, const float* __restrict__ b0,
    const float* __restrict__ g0, const float* __restrict__ be0,
    const float* __restrict__ w1, const float* __restrict__ b1,
    const float* __restrict__ g1, const float* __restrict__ be1,
    const float* __restrict__ w2, const float* __restrict__ b2,
    int* __restrict__ gidx, float* __restrict__ wbuf){
  const int bm = blockIdx.x;
  const int b  = bm >> 8;
  const int c  = threadIdx.x;
  __shared__ int   sidx[SS];
  __shared__ float sgx[3][SS];
  __shared__ float sh0[SS][WCC];
  __shared__ float sh1[SS][WCC];

  const float w0r0 = w0[c*3+0], w0r1 = w0[c*3+1], w0r2 = w0[c*3+2];
  const float b0c=b0[c], g0c=g0[c], be0c=be0[c];
  const float b1c=b1[c], g1c=g1[c], be1c=be1[c], b2c=b2[c];
  float w1r[64], w2r[64];
#pragma unroll
  for (int i=0;i<16;i++){
    float4 v = *(const float4*)(w1 + c*64 + i*4);
    w1r[i*4+0]=v.x; w1r[i*4+1]=v.y; w1r[i*4+2]=v.z; w1r[i*4+3]=v.w;
    float4 u = *(const float4*)(w2 + c*64 + i*4);
    w2r[i*4+0]=u.x; w2r[i*4+1]=u.y; w2r[i*4+2]=u.z; w2r[i*4+3]=u.w;
  }
  const float cx = nxyz[bm*3+0], cy = nxyz[bm*3+1], cz = nxyz[bm*3+2];
  const float* xb = xyz + (size_t)b*NN*3;
  const float R2 = (float)(0.4*0.4);
  int cnt = 0;
  for (int n0=0; n0<NN && cnt<SS; n0+=64){
    int n = n0 + c;
    float dx = xb[n*3+0]-cx, dy = xb[n*3+1]-cy, dz = xb[n*3+2]-cz;
    float d2 = dx*dx+dy*dy+dz*dz;
    bool in = (d2 <= R2);
    unsigned long long mk = __ballot(in);
    int rank = cnt + (int)__popcll(mk & ((1ull<<c)-1ull));
    if (in && rank < SS) sidx[rank] = n;
    cnt += (int)__popcll(mk);
  }
  int total = min(cnt, SS);
  __syncthreads();
  int i0 = sidx[0];
  if (c >= total && c < SS) sidx[c] = i0;
  __syncthreads();
  if (c < SS){
    int p = sidx[c];
    gidx[bm*SS + c] = p;
    sgx[0][c] = xb[p*3+0]-cx;
    sgx[1][c] = xb[p*3+1]-cy;
    sgx[2][c] = xb[p*3+2]-cz;
  }
  __syncthreads();
  // layer 0: h0[s][c]
  for (int s=0;s<SS;s++){
    float pre = w0r0*sgx[0][s] + w0r1*sgx[1][s] + w0r2*sgx[2][s] + b0c;
    sh0[s][c] = fmaxf(bnf(pre, g0c, be0c), 0.f);
  }
  __syncthreads();
  // layer 1: uniform-broadcast float4 LDS reads of h0 rows
  for (int s=0;s<SS;s++){
    float a = b1c;
#pragma unroll
    for (int k=0;k<64;k+=4){
      float4 h = *(const float4*)(&sh0[s][k]);
      a += w1r[k]*h.x + w1r[k+1]*h.y + w1r[k+2]*h.z + w1r[k+3]*h.w;
    }
    sh1[s][c] = fmaxf(bnf(a, g1c, be1c), 0.f);
  }
  __syncthreads();
  // layer 2 -> weights out
  float* wb = wbuf + (size_t)bm*SS*WCC;
  for (int s=0;s<SS;s++){
    float a = b2c;
#pragma unroll
    for (int k=0;k<64;k+=4){
      float4 h = *(const float4*)(&sh1[s][k]);
      a += w2r[k]*h.x + w2r[k+1]*h.y + w2r[k+2]*h.z + w2r[k+3]*h.w;
    }
    wb[s*WCC + c] = a;
  }
}

// ---------------- aggregation: agg[bm, d*64+w] = sum_s feat[d,s]*wt[w,s] ----------------
__global__ __launch_bounds__(256) void k_agg(const float* __restrict__ featT,
                                             const float* __restrict__ wbuf,
                                             const int* __restrict__ gidx,
                                             float* __restrict__ agg){
  const int bm = blockIdx.x;
  const int b  = bm >> 8;
  __shared__ float wt[SS][WCC];
  __shared__ int   sidx[SS];
  const int t = threadIdx.x;
  const float* wsrc = wbuf + (size_t)bm*SS*WCC;
#pragma unroll
  for (int i=0;i<8;i++){
    int li = t + i*256;
    ((float*)wt)[li] = wsrc[li];
  }
  if (t < SS) sidx[t] = gidx[bm*SS + t];
  __syncthreads();
  const int d  = t & 63;
  const int wg = t >> 6;
  float acc[16];
#pragma unroll
  for (int j=0;j<16;j++) acc[j]=0.f;
  const float* fb = featT + (size_t)b*NN*DD;
  for (int s=0;s<SS;s++){
    float fv = fb[(size_t)sidx[s]*DD + d];
#pragma unroll
    for (int j=0;j<16;j++) acc[j] += fv * wt[s][wg*16+j];
  }
  float* ab = agg + (size_t)bm*4096 + d*64 + wg*16;
#pragma unroll
  for (int j=0;j<16;j+=4){
    *(float4*)(ab+j) = make_float4(acc[j],acc[j+1],acc[j+2],acc[j+3]);
  }
}

// ---------------- new_feature GEMM, split-K partial: part[ks][row][o] ----------------
__global__ __launch_bounds__(256) void k_nf_part(const float* __restrict__ agg, const float* __restrict__ wlT,
    float* __restrict__ part){
  const int blk = blockIdx.x;
  const int rb  = blk >> 2;          // 64 row-blocks
  const int ks  = blk & 3;           // 4 K-slices
  const int row0 = rb * 64;
  const int kbase = ks * 1024;
  __shared__ float As[64][65];
  __shared__ float Bs[64][128];
  const int t = threadIdx.x;
  float acc[4][8];
#pragma unroll
  for (int i=0;i<4;i++)
#pragma unroll
    for (int j=0;j<8;j++) acc[i][j]=0.f;
  const int mg = t >> 4, og = t & 15;
  for (int k0=kbase; k0<kbase+1024; k0+=64){
    {
      const int r = t >> 2, c0 = (t & 3) << 4;
      const float* src = agg + (size_t)(row0 + r)*4096 + k0 + c0;
#pragma unroll
      for (int i=0;i<16;i+=4){
        float4 v = *(const float4*)(src+i);
        As[r][c0+i+0]=v.x; As[r][c0+i+1]=v.y; As[r][c0+i+2]=v.z; As[r][c0+i+3]=v.w;
      }
    }
#pragma unroll
    for (int ch=0; ch<8; ch++){
      int li = ch*1024 + t*4;
      int kk = li >> 7, o = li & 127;
      float4 v = *(const float4*)(wlT + (size_t)(k0+kk)*128 + o);
      *(float4*)(&Bs[kk][o]) = v;
    }
    __syncthreads();
#pragma unroll 8
    for (int kk=0; kk<64; kk++){
      float a0 = As[mg*4+0][kk], a1 = As[mg*4+1][kk], a2 = As[mg*4+2][kk], a3 = As[mg*4+3][kk];
      float4 bA = *(float4*)(&Bs[kk][og*8]);
      float4 bB = *(float4*)(&Bs[kk][og*8+4]);
      float bb[8] = {bA.x,bA.y,bA.z,bA.w,bB.x,bB.y,bB.z,bB.w};
#pragma unroll
      for (int j=0;j<8;j++){
        acc[0][j] += a0*bb[j];
        acc[1][j] += a1*bb[j];
        acc[2][j] += a2*bb[j];
        acc[3][j] += a3*bb[j];
      }
    }
    __syncthreads();
  }
  float* pb = part + ((size_t)ks << 19);   // 4096*128 per slice
#pragma unroll
  for (int i=0;i<4;i++){
    const int row = row0 + mg*4 + i;
    float* dst = pb + (size_t)row*128 + og*8;
    *(float4*)(dst)   = make_float4(acc[i][0],acc[i][1],acc[i][2],acc[i][3]);
    *(float4*)(dst+4) = make_float4(acc[i][4],acc[i][5],acc[i][6],acc[i][7]);
  }
}

// ---------------- nf epilogue: sum 4 partials + bias + bn + relu ----------------
__global__ __launch_bounds__(256) void k_nf_ep(const float* __restrict__ part,
    const float* __restrict__ bl, const float* __restrict__ gl, const float* __restrict__ bel,
    float* __restrict__ nfT){
  const int gid = blockIdx.x*256 + threadIdx.x;
  const int base = gid*4;
  const int o0 = base & 127;
  float4 s0 = *(const float4*)(part + base);
  float4 s1 = *(const float4*)(part + (1<<19) + base);
  float4 s2 = *(const float4*)(part + (2<<19) + base);
  float4 s3 = *(const float4*)(part + (3<<19) + base);
  float sum[4] = {s0.x+s1.x+s2.x+s3.x, s0.y+s1.y+s2.y+s3.y,
                  s0.z+s1.z+s2.z+s3.z, s0.w+s1.w+s2.w+s3.w};
  float ov[4];
#pragma unroll
  for (int j=0;j<4;j++){
    const int o = o0 + j;
    ov[j] = fmaxf(bnf(sum[j] + bl[o], gl[o], bel[o]), 0.f);
  }
  *(float4*)(nfT + base) = make_float4(ov[0],ov[1],ov[2],ov[3]);
}

// ---------------- 3-NN + interpolation -> interpT (B,N,128) ----------------
__global__ __launch_bounds__(256) void k_3nn(const float* __restrict__ xyz, const float* __restrict__ nxyz,
    const float* __restrict__ nfT, float* __restrict__ interpT){
  const int blk = blockIdx.x;
  const int b  = blk >> 5;
  const int n0 = (blk & 31) << 8;
  __shared__ float snew[MM][3];
  __shared__ float sw[256][3];
  __shared__ int   si[256][3];
  const int t = threadIdx.x;
  if (t < 192){
    float4 v = *(const float4*)(nxyz + (size_t)b*MM*3 + t*4);
    ((float*)snew)[t*4+0]=v.x; ((float*)snew)[t*4+1]=v.y; ((float*)snew)[t*4+2]=v.z; ((float*)snew)[t*4+3]=v.w;
  }
  __syncthreads();
  {
    const int n = n0 + t;
    const float x = xyz[((size_t)b*NN+n)*3+0];
    const float y = xyz[((size_t)b*NN+n)*3+1];
    const float z = xyz[((size_t)b*NN+n)*3+2];
    float d1=1e30f, d2=1e30f, d3=1e30f; int i1=0,i2=0,i3=0;
    for (int m=0;m<MM;m++){
      float dx=x-snew[m][0], dy=y-snew[m][1], dz=z-snew[m][2];
      float d = dx*dx+dy*dy+dz*dz;
      if (d < d3){
        if (d < d1){ d3=d2;i3=i2; d2=d1;i2=i1; d1=d;i1=m; }
        else if (d < d2){ d3=d2;i3=i2; d2=d;i2=m; }
        else { d3=d;i3=m; }
      }
    }
    float r1=1.f/(d1+1e-8f), r2=1.f/(d2+1e-8f), r3=1.f/(d3+1e-8f);
    float rs = 1.f/(r1+r2+r3);
    sw[t][0]=r1*rs; sw[t][1]=r2*rs; sw[t][2]=r3*rs;
    si[t][0]=i1; si[t][1]=i2; si[t][2]=i3;
  }
  __syncthreads();
  const int c = t & 127, half = t >> 7;
  for (int r=0;r<128;r++){
    const int nn = r*2 + half;
    const float w0v=sw[nn][0], w1v=sw[nn][1], w2v=sw[nn][2];
    const float* p0 = nfT + ((size_t)b*MM + si[nn][0])*128;
    const float* p1 = nfT + ((size_t)b*MM + si[nn][1])*128;
    const float* p2 = nfT + ((size_t)b*MM + si[nn][2])*128;
    interpT[((size_t)b*NN + n0 + nn)*128 + c] = w0v*p0[c] + w1v*p1[c] + w2v*p2[c];
  }
}

// ---------------- final conv: out[b,o,n] = relu(bn(wf @ [interp;feature] + bf)) ----------------
__global__ __launch_bounds__(256) void k_final(const float* __restrict__ interpT, const float* __restrict__ feature,
    const float* __restrict__ wfT,
    const float* __restrict__ bf, const float* __restrict__ gf, const float* __restrict__ bef,
    float* __restrict__ out){
  const int blk = blockIdx.x;
  const int b  = blk >> 6;
  const int n0 = (blk & 63) << 7;
  __shared__ float Wsh[32][128];
  __shared__ float Csh[32][132];
  const int t = threadIdx.x;
  float acc[8][8];
#pragma unroll
  for (int i=0;i<8;i++)
#pragma unroll
    for (int j=0;j<8;j++) acc[i][j]=0.f;
  const int og = t >> 4, ng = t & 15;
  for (int k0=0; k0<192; k0+=32){
    {
      const int kk = t >> 3, o0 = (t & 7) << 4;
#pragma unroll
      for (int i=0;i<16;i+=4)
        *(float4*)(&Wsh[kk][o0+i]) = *(const float4*)(wfT + (size_t)(k0+kk)*128 + o0 + i);
    }
    if (k0 < 128){
      const int nn = t >> 1, kb = (t & 1) << 4;
      const float* src = interpT + ((size_t)b*NN + n0 + nn)*128 + k0 + kb;
#pragma unroll
      for (int i=0;i<16;i+=4){
        float4 v = *(const float4*)(src+i);
        Csh[kb+i+0][nn]=v.x; Csh[kb+i+1][nn]=v.y; Csh[kb+i+2][nn]=v.z; Csh[kb+i+3][nn]=v.w;
      }
    } else {
      const int kk = t >> 3, nb = (t & 7) << 4;
      const float* src = feature + ((size_t)b*DD + (k0-128) + kk)*NN + n0 + nb;
#pragma unroll
      for (int i=0;i<16;i+=4){
        float4 v = *(const float4*)(src+i);
        *(float4*)(&Csh[kk][nb+i]) = v;
      }
    }
    __syncthreads();
#pragma unroll 8
    for (int kk=0;kk<32;kk++){
      float4 a0 = *(float4*)(&Wsh[kk][og*8]);
      float4 a1 = *(float4*)(&Wsh[kk][og*8+4]);
      float av[8] = {a0.x,a0.y,a0.z,a0.w,a1.x,a1.y,a1.z,a1.w};
      float4 c0 = *(float4*)(&Csh[kk][ng*8]);
      float4 c1 = *(float4*)(&Csh[kk][ng*8+4]);
      float cv[8] = {c0.x,c0.y,c0.z,c0.w,c1.x,c1.y,c1.z,c1.w};
#pragma unroll
      for (int i=0;i<8;i++)
#pragma unroll
        for (int j=0;j<8;j++)
          acc[i][j] += av[i]*cv[j];
    }
    __syncthreads();
  }
#pragma unroll
  for (int i=0;i<8;i++){
    const int o = og*8 + i;
    const float bfo = bf[o], gfo = gf[o], befo = bef[o];
    float ov[8];
#pragma unroll
    for (int j=0;j<8;j++) ov[j] = fmaxf(bnf(acc[i][j] + bfo, gfo, befo), 0.f);
    float* dst = out + ((size_t)b*OUTC + o)*NN + n0 + ng*8;
    *(float4*)(dst)   = make_float4(ov[0],ov[1],ov[2],ov[3]);
    *(float4*)(dst+4) = make_float4(ov[4],ov[5],ov[6],ov[7]);
  }
}

extern "C" void kernel_launch(void* const* d_in, const int* in_sizes, int n_in,
                              void* d_out, int out_size, void* d_ws, size_t ws_size,
                              hipStream_t stream){
  const float* xyz     = (const float*)d_in[0];
  const float* feature = (const float*)d_in[1];
  const float* w0  = (const float*)d_in[2];
  const float* b0  = (const float*)d_in[3];
  const float* g0  = (const float*)d_in[4];
  const float* be0 = (const float*)d_in[5];
  const float* w1  = (const float*)d_in[6];
  const float* b1  = (const float*)d_in[7];
  const float* g1  = (const float*)d_in[8];
  const float* be1 = (const float*)d_in[9];
  const float* w2  = (const float*)d_in[10];
  const float* b2  = (const float*)d_in[11];
  const float* wl  = (const float*)d_in[12];
  const float* bl  = (const float*)d_in[13];
  const float* gl  = (const float*)d_in[14];
  const float* bel = (const float*)d_in[15];
  const float* wf  = (const float*)d_in[16];
  const float* bf  = (const float*)d_in[17];
  const float* gf  = (const float*)d_in[18];
  const float* bef = (const float*)d_in[19];
  float* out = (float*)d_out;

  char* ws = (char*)d_ws;
  float* featT = (float*)(ws + 0);          // 33,554,432 B
  float* wbuf  = (float*)(ws + 33554432);   // 33,554,432 B (dead after k_agg)
  float* part  = (float*)(ws + 33554432);   // 8 MB, reuses wbuf region after k_agg
  float* agg   = (float*)(ws + 67108864);   // 67,108,864 B
  float* wlT   = (float*)(ws + 134217728);  //  2,097,152 B
  float* wfT   = (float*)(ws + 136314880);  //     98,304 B
  float* nxyz  = (float*)(ws + 136429568);  //     49,152 B
  int*   gidx  = (int*)  (ws + 136478720);  //    524,288 B
  float* nfT   = (float*)(ws + 137003008);  //  2,097,152 B
  float* interpT = (float*)(ws + 0);        // 67 MB, aliases featT+wbuf/part (dead by then)

  k_tf     <<<2048, 256, 0, stream>>>(feature, featT);
  k_twl    <<<2048, 256, 0, stream>>>(wl, wlT);
  k_twf    <<<96,   256, 0, stream>>>(wf, wfT);
  k_fps    <<<BB,   256, 0, stream>>>(xyz, nxyz);
  k_bq_mlp <<<BB*MM, 64, 0, stream>>>(xyz, nxyz, w0,b0,g0,be0, w1,b1,g1,be1, w2,b2, gidx, wbuf);
  k_agg    <<<BB*MM, 256, 0, stream>>>(featT, wbuf, gidx, agg);
  k_nf_part<<<256,  256, 0, stream>>>(agg, wlT, part);
  k_nf_ep  <<<512,  256, 0, stream>>>(part, bl, gl, bel, nfT);
  k_3nn    <<<BB*(NN/256), 256, 0, stream>>>(xyz, nxyz, nfT, interpT);
  k_final  <<<BB*(NN/128), 256, 0, stream>>>(interpT, feature, wfT, bf, gf, bef, out);
}

// Round 4
// 616.152 us; speedup vs baseline: 1.9305x; 1.0422x over previous
//
#include <hip/hip_runtime.h>
#include <hip/hip_bf16.h>
#include <cstdint>
#include <cstddef>

#define BB   16
#define NN   8192
#define DD   64
#define MM   256
#define SS   32
#define OUTC 128
#define WCC  64

using short8 = __attribute__((ext_vector_type(8))) short;
using f32x4  = __attribute__((ext_vector_type(4))) float;

__device__ __forceinline__ float bnf(float x, float g, float be){
    const float BNS = 0.99999500003749969f; // 1/sqrt(1+1e-5)
    return g * (x * BNS) + be;
}
__device__ __forceinline__ unsigned short f2bf(float f){
    __hip_bfloat16 h = __float2bfloat16(f);
    return *reinterpret_cast<unsigned short*>(&h);
}

// ---------------- feature transpose (B,D,N) -> (B,N,D) ----------------
__global__ __launch_bounds__(256) void k_tf(const float* __restrict__ f, float* __restrict__ fT){
  const int blk = blockIdx.x;
  const int b  = blk >> 7;
  const int n0 = (blk & 127) << 6;
  __shared__ float tile[64][65];
  const int t = threadIdx.x;
  {
    const int d = t >> 2, j0 = (t & 3) << 4;
    const float* src = f + ((size_t)b*DD + d)*NN + n0 + j0;
#pragma unroll
    for (int i=0;i<16;i+=4){
      float4 v = *(const float4*)(src + i);
      tile[d][j0+i+0]=v.x; tile[d][j0+i+1]=v.y; tile[d][j0+i+2]=v.z; tile[d][j0+i+3]=v.w;
    }
  }
  __syncthreads();
  {
    const int j = t >> 2, d0 = (t & 3) << 4;
    float* dst = fT + ((size_t)b*NN + n0 + j)*DD + d0;
#pragma unroll
    for (int i=0;i<16;i+=4){
      float4 v = make_float4(tile[d0+i][j], tile[d0+i+1][j], tile[d0+i+2][j], tile[d0+i+3][j]);
      *(float4*)(dst + i) = v;
    }
  }
}

// ---------------- wl cast to bf16 (same [o][k] layout) ----------------
__global__ __launch_bounds__(256) void k_twl(const float* __restrict__ wl, unsigned short* __restrict__ wlB){
  int idx = (blockIdx.x*256 + threadIdx.x)*4;
  float4 v = *(const float4*)(wl + idx);
  ushort4 h = make_ushort4(f2bf(v.x), f2bf(v.y), f2bf(v.z), f2bf(v.w));
  *(ushort4*)(wlB + idx) = h;
}
__global__ __launch_bounds__(256) void k_twf(const float* __restrict__ wf, float* __restrict__ wfT){
  int idx = blockIdx.x*256 + threadIdx.x;
  if (idx < 192*OUTC){
    int k = idx >> 7, o = idx & 127;
    wfT[idx] = wf[o*192 + k];
  }
}

// ---------------- farthest point sampling (512 thr, packed-u64, 1 barrier/step) ----------------
__global__ __launch_bounds__(512) void k_fps(const float* __restrict__ xyz,
                                             float* __restrict__ nxyz){
  const int b = blockIdx.x;
  const int t = threadIdx.x;
  const float* xb = xyz + (size_t)b*NN*3;
  __shared__ float sxyz[NN*3];   // 96 KB
  __shared__ float snew[MM*3];   // 3 KB
  __shared__ unsigned long long skey[2][8];
  for (int i = t; i < NN*3; i += 512) sxyz[i] = xb[i];
  float px[16], py[16], pz[16], dist[16];
#pragma unroll
  for (int i=0;i<16;i++){
    int id = i*512 + t;
    px[i] = xb[id*3+0]; py[i] = xb[id*3+1]; pz[i] = xb[id*3+2];
    dist[i] = 1e10f;
  }
  __syncthreads();
  float lx = sxyz[0], ly = sxyz[1], lz = sxyz[2];
  if (t==0){ snew[0]=lx; snew[1]=ly; snew[2]=lz; }
  for (int step=1; step<MM; ++step){
    float bv = 0.0f; int bi = NN-1;
#pragma unroll
    for (int i=0;i<16;i++){
      float dx=px[i]-lx, dy=py[i]-ly, dz=pz[i]-lz;
      float d = dx*dx + dy*dy + dz*dz;
      float nd = fminf(dist[i], d);
      dist[i] = nd;
      bool gt = nd > bv;
      bv = gt ? nd : bv;
      bi = gt ? (i*512 + t) : bi;
    }
    unsigned long long key = ((unsigned long long)__float_as_uint(bv) << 32) | (unsigned)(NN-1 - bi);
#pragma unroll
    for (int off=1; off<64; off<<=1){
      unsigned long long ok = __shfl_xor(key, off, 64);
      if (ok > key) key = ok;
    }
    const int p = step & 1;
    if ((t & 63) == 0) skey[p][t>>6] = key;
    __syncthreads();   // single barrier per step
    unsigned long long k0=skey[p][0], k1=skey[p][1], k2=skey[p][2], k3=skey[p][3];
    unsigned long long k4=skey[p][4], k5=skey[p][5], k6=skey[p][6], k7=skey[p][7];
    unsigned long long ka = k0>k1?k0:k1, kb2 = k2>k3?k2:k3;
    unsigned long long kc = k4>k5?k4:k5, kd = k6>k7?k6:k7;
    unsigned long long ke = ka>kb2?ka:kb2, kf = kc>kd?kc:kd;
    unsigned long long kw = ke>kf?ke:kf;
    const int bid = (NN-1) - (int)(unsigned)(kw & 0xFFFFFFFFull);
    lx = sxyz[bid*3+0]; ly = sxyz[bid*3+1]; lz = sxyz[bid*3+2];
    if (t==0){ snew[step*3+0]=lx; snew[step*3+1]=ly; snew[step*3+2]=lz; }
  }
  __syncthreads();
  for (int i = t; i < MM*3; i += 512) nxyz[(size_t)b*MM*3 + i] = snew[i];
}

// ---------------- ball query + 3-layer MLP (LDS-staged) ----------------
__global__ __launch_bounds__(64) void k_bq_mlp(const float* __restrict__ xyz,
    const float* __restrict__ nxyz,
    const float* __restrict__ w0, const float* __restrict__ b0,
    const float* __restrict__ g0, const float* __restrict__ be0,
    const float* __restrict__ w1, const float* __restrict__ b1,
    const float* __restrict__ g1, const float* __restrict__ be1,
    const float* __restrict__ w2, const float* __restrict__ b2,
    int* __restrict__ gidx, float* __restrict__ wbuf){
  const int bm = blockIdx.x;
  const int b  = bm >> 8;
  const int c  = threadIdx.x;
  __shared__ int   sidx[SS];
  __shared__ float sgx[3][SS];
  __shared__ float sh0[SS][WCC];
  __shared__ float sh1[SS][WCC];

  const float w0r0 = w0[c*3+0], w0r1 = w0[c*3+1], w0r2 = w0[c*3+2];
  const float b0c=b0[c], g0c=g0[c], be0c=be0[c];
  const float b1c=b1[c], g1c=g1[c], be1c=be1[c], b2c=b2[c];
  float w1r[64], w2r[64];
#pragma unroll
  for (int i=0;i<16;i++){
    float4 v = *(const float4*)(w1 + c*64 + i*4);
    w1r[i*4+0]=v.x; w1r[i*4+1]=v.y; w1r[i*4+2]=v.z; w1r[i*4+3]=v.w;
    float4 u = *(const float4*)(w2 + c*64 + i*4);
    w2r[i*4+0]=u.x; w2r[i*4+1]=u.y; w2r[i*4+2]=u.z; w2r[i*4+3]=u.w;
  }
  const float cx = nxyz[bm*3+0], cy = nxyz[bm*3+1], cz = nxyz[bm*3+2];
  const float* xb = xyz + (size_t)b*NN*3;
  const float R2 = (float)(0.4*0.4);
  int cnt = 0;
  for (int n0=0; n0<NN && cnt<SS; n0+=64){
    int n = n0 + c;
    float dx = xb[n*3+0]-cx, dy = xb[n*3+1]-cy, dz = xb[n*3+2]-cz;
    float d2 = dx*dx+dy*dy+dz*dz;
    bool in = (d2 <= R2);
    unsigned long long mk = __ballot(in);
    int rank = cnt + (int)__popcll(mk & ((1ull<<c)-1ull));
    if (in && rank < SS) sidx[rank] = n;
    cnt += (int)__popcll(mk);
  }
  int total = min(cnt, SS);
  __syncthreads();
  int i0 = sidx[0];
  if (c >= total && c < SS) sidx[c] = i0;
  __syncthreads();
  if (c < SS){
    int p = sidx[c];
    gidx[bm*SS + c] = p;
    sgx[0][c] = xb[p*3+0]-cx;
    sgx[1][c] = xb[p*3+1]-cy;
    sgx[2][c] = xb[p*3+2]-cz;
  }
  __syncthreads();
  for (int s=0;s<SS;s++){
    float pre = w0r0*sgx[0][s] + w0r1*sgx[1][s] + w0r2*sgx[2][s] + b0c;
    sh0[s][c] = fmaxf(bnf(pre, g0c, be0c), 0.f);
  }
  __syncthreads();
  for (int s=0;s<SS;s++){
    float a = b1c;
#pragma unroll
    for (int k=0;k<64;k+=4){
      float4 h = *(const float4*)(&sh0[s][k]);
      a += w1r[k]*h.x + w1r[k+1]*h.y + w1r[k+2]*h.z + w1r[k+3]*h.w;
    }
    sh1[s][c] = fmaxf(bnf(a, g1c, be1c), 0.f);
  }
  __syncthreads();
  float* wb = wbuf + (size_t)bm*SS*WCC;
  for (int s=0;s<SS;s++){
    float a = b2c;
#pragma unroll
    for (int k=0;k<64;k+=4){
      float4 h = *(const float4*)(&sh1[s][k]);
      a += w2r[k]*h.x + w2r[k+1]*h.y + w2r[k+2]*h.z + w2r[k+3]*h.w;
    }
    wb[s*WCC + c] = a;
  }
}

// ---------------- aggregation -> agg in bf16 [4096][4096] ----------------
__global__ __launch_bounds__(256) void k_agg(const float* __restrict__ featT,
                                             const float* __restrict__ wbuf,
                                             const int* __restrict__ gidx,
                                             unsigned short* __restrict__ aggB){
  const int bm = blockIdx.x;
  const int b  = bm >> 8;
  __shared__ float wt[SS][WCC];
  __shared__ int   sidx[SS];
  const int t = threadIdx.x;
  const float* wsrc = wbuf + (size_t)bm*SS*WCC;
#pragma unroll
  for (int i=0;i<8;i++){
    int li = t + i*256;
    ((float*)wt)[li] = wsrc[li];
  }
  if (t < SS) sidx[t] = gidx[bm*SS + t];
  __syncthreads();
  const int d  = t & 63;
  const int wg = t >> 6;
  float acc[16];
#pragma unroll
  for (int j=0;j<16;j++) acc[j]=0.f;
  const float* fb = featT + (size_t)b*NN*DD;
  for (int s=0;s<SS;s++){
    float fv = fb[(size_t)sidx[s]*DD + d];
#pragma unroll
    for (int j=0;j<16;j++) acc[j] += fv * wt[s][wg*16+j];
  }
  unsigned short h[16];
#pragma unroll
  for (int j=0;j<16;j++) h[j] = f2bf(acc[j]);
  unsigned short* ab = aggB + (size_t)bm*4096 + d*64 + wg*16;
  *(uint4*)(ab)     = *(uint4*)(&h[0]);
  *(uint4*)(ab + 8) = *(uint4*)(&h[8]);
}

// ---------------- new_feature GEMM via MFMA bf16, split-K partials ----------------
__global__ __launch_bounds__(256) void k_nf_part(const unsigned short* __restrict__ aggB,
                                                 const unsigned short* __restrict__ wlB,
                                                 float* __restrict__ part){
  const int blk = blockIdx.x;
  const int rb  = blk >> 2;          // 64 row-blocks (64 rows each)
  const int ks  = blk & 3;           // 4 K-slices of 1024
  const int wid = threadIdx.x >> 6, lane = threadIdx.x & 63;
  const int m0 = rb*64 + wid*16;
  const int r  = lane & 15, kg = lane >> 4;
  f32x4 acc[8];
#pragma unroll
  for (int i=0;i<8;i++) acc[i] = (f32x4){0.f,0.f,0.f,0.f};
  const short* arow = (const short*)aggB + (size_t)(m0 + r)*4096 + ks*1024 + kg*8;
  const short* brow = (const short*)wlB  + (size_t)r*4096        + ks*1024 + kg*8;
#pragma unroll 4
  for (int kc=0; kc<32; kc++){
    short8 a = *(const short8*)(arow + kc*32);
#pragma unroll
    for (int ot=0; ot<8; ot++){
      short8 bfr = *(const short8*)(brow + (size_t)ot*16*4096 + kc*32);
      acc[ot] = __builtin_amdgcn_mfma_f32_16x16x32_bf16(a, bfr, acc[ot], 0, 0, 0);
    }
  }
  float* pb = part + ((size_t)ks << 19);
#pragma unroll
  for (int ot=0; ot<8; ot++){
#pragma unroll
    for (int rr=0; rr<4; rr++){
      int row = m0 + kg*4 + rr;
      pb[(size_t)row*128 + ot*16 + r] = acc[ot][rr];
    }
  }
}

// ---------------- nf epilogue: sum 4 partials + bias + bn + relu ----------------
__global__ __launch_bounds__(256) void k_nf_ep(const float* __restrict__ part,
    const float* __restrict__ bl, const float* __restrict__ gl, const float* __restrict__ bel,
    float* __restrict__ nfT){
  const int gid = blockIdx.x*256 + threadIdx.x;
  const int base = gid*4;
  const int o0 = base & 127;
  float4 s0 = *(const float4*)(part + base);
  float4 s1 = *(const float4*)(part + (1<<19) + base);
  float4 s2 = *(const float4*)(part + (2<<19) + base);
  float4 s3 = *(const float4*)(part + (3<<19) + base);
  float sum[4] = {s0.x+s1.x+s2.x+s3.x, s0.y+s1.y+s2.y+s3.y,
                  s0.z+s1.z+s2.z+s3.z, s0.w+s1.w+s2.w+s3.w};
  float ov[4];
#pragma unroll
  for (int j=0;j<4;j++){
    const int o = o0 + j;
    ov[j] = fmaxf(bnf(sum[j] + bl[o], gl[o], bel[o]), 0.f);
  }
  *(float4*)(nfT + base) = make_float4(ov[0],ov[1],ov[2],ov[3]);
}

// ---------------- fused: 3-NN interp + final conv ----------------
__global__ __launch_bounds__(256) void k_final(const float* __restrict__ xyz,
    const float* __restrict__ nxyz, const float* __restrict__ nfT,
    const float* __restrict__ feature, const float* __restrict__ wfT,
    const float* __restrict__ bf, const float* __restrict__ gf, const float* __restrict__ bef,
    float* __restrict__ out){
  const int blk = blockIdx.x;
  const int b  = blk >> 6;
  const int n0 = (blk & 63) << 7;
  __shared__ float Wsh[32][128];
  __shared__ float Csh[32][132];
  __shared__ float snew[MM*3];
  __shared__ float sw[128][3];
  __shared__ int   si[128][3];
  const int t = threadIdx.x;
  if (t < 192){
    float4 v = *(const float4*)(nxyz + (size_t)b*MM*3 + t*4);
    snew[t*4+0]=v.x; snew[t*4+1]=v.y; snew[t*4+2]=v.z; snew[t*4+3]=v.w;
  }
  __syncthreads();
  if (t < 128){
    const int n = n0 + t;
    const float x = xyz[((size_t)b*NN+n)*3+0];
    const float y = xyz[((size_t)b*NN+n)*3+1];
    const float z = xyz[((size_t)b*NN+n)*3+2];
    float d1=1e30f, d2=1e30f, d3=1e30f; int i1=0,i2=0,i3=0;
    for (int m=0;m<MM;m++){
      float dx=x-snew[m*3+0], dy=y-snew[m*3+1], dz=z-snew[m*3+2];
      float d = dx*dx+dy*dy+dz*dz;
      if (d < d3){
        if (d < d1){ d3=d2;i3=i2; d2=d1;i2=i1; d1=d;i1=m; }
        else if (d < d2){ d3=d2;i3=i2; d2=d;i2=m; }
        else { d3=d;i3=m; }
      }
    }
    float r1=1.f/(d1+1e-8f), r2=1.f/(d2+1e-8f), r3=1.f/(d3+1e-8f);
    float rs = 1.f/(r1+r2+r3);
    sw[t][0]=r1*rs; sw[t][1]=r2*rs; sw[t][2]=r3*rs;
    si[t][0]=i1; si[t][1]=i2; si[t][2]=i3;
  }
  __syncthreads();

  float acc[8][8];
#pragma unroll
  for (int i=0;i<8;i++)
#pragma unroll
    for (int j=0;j<8;j++) acc[i][j]=0.f;
  const int og = t >> 4, ng = t & 15;
  const float* nfb = nfT + (size_t)b*MM*128;
  for (int k0=0; k0<192; k0+=32){
    {
      const int kk = t >> 3, o0 = (t & 7) << 4;
#pragma unroll
      for (int i=0;i<16;i+=4)
        *(float4*)(&Wsh[kk][o0+i]) = *(const float4*)(wfT + (size_t)(k0+kk)*128 + o0 + i);
    }
    if (k0 < 128){
      // interp on the fly: Csh[kb][nn] = sum_j w_j * nfT[i_j][k0+kb]
      const int nn = t >> 1, kb0 = (t & 1) << 4;
      const float w0v = sw[nn][0], w1v = sw[nn][1], w2v = sw[nn][2];
      const float* p0 = nfb + (size_t)si[nn][0]*128 + k0 + kb0;
      const float* p1 = nfb + (size_t)si[nn][1]*128 + k0 + kb0;
      const float* p2 = nfb + (size_t)si[nn][2]*128 + k0 + kb0;
#pragma unroll
      for (int i=0;i<16;i+=4){
        float4 a = *(const float4*)(p0+i);
        float4 bq = *(const float4*)(p1+i);
        float4 cq = *(const float4*)(p2+i);
        Csh[kb0+i+0][nn] = w0v*a.x + w1v*bq.x + w2v*cq.x;
        Csh[kb0+i+1][nn] = w0v*a.y + w1v*bq.y + w2v*cq.y;
        Csh[kb0+i+2][nn] = w0v*a.z + w1v*bq.z + w2v*cq.z;
        Csh[kb0+i+3][nn] = w0v*a.w + w1v*bq.w + w2v*cq.w;
      }
    } else {
      const int kk = t >> 3, nb = (t & 7) << 4;
      const float* src = feature + ((size_t)b*DD + (k0-128) + kk)*NN + n0 + nb;
#pragma unroll
      for (int i=0;i<16;i+=4){
        float4 v = *(const float4*)(src+i);
        *(float4*)(&Csh[kk][nb+i]) = v;
      }
    }
    __syncthreads();
#pragma unroll 8
    for (int kk=0;kk<32;kk++){
      float4 a0 = *(float4*)(&Wsh[kk][og*8]);
      float4 a1 = *(float4*)(&Wsh[kk][og*8+4]);
      float av[8] = {a0.x,a0.y,a0.z,a0.w,a1.x,a1.y,a1.z,a1.w};
      float4 c0 = *(float4*)(&Csh[kk][ng*8]);
      float4 c1 = *(float4*)(&Csh[kk][ng*8+4]);
      float cv[8] = {c0.x,c0.y,c0.z,c0.w,c1.x,c1.y,c1.z,c1.w};
#pragma unroll
      for (int i=0;i<8;i++)
#pragma unroll
        for (int j=0;j<8;j++)
          acc[i][j] += av[i]*cv[j];
    }
    __syncthreads();
  }
#pragma unroll
  for (int i=0;i<8;i++){
    const int o = og*8 + i;
    const float bfo = bf[o], gfo = gf[o], befo = bef[o];
    float ov[8];
#pragma unroll
    for (int j=0;j<8;j++) ov[j] = fmaxf(bnf(acc[i][j] + bfo, gfo, befo), 0.f);
    float* dst = out + ((size_t)b*OUTC + o)*NN + n0 + ng*8;
    *(float4*)(dst)   = make_float4(ov[0],ov[1],ov[2],ov[3]);
    *(float4*)(dst+4) = make_float4(ov[4],ov[5],ov[6],ov[7]);
  }
}

extern "C" void kernel_launch(void* const* d_in, const int* in_sizes, int n_in,
                              void* d_out, int out_size, void* d_ws, size_t ws_size,
                              hipStream_t stream){
  const float* xyz     = (const float*)d_in[0];
  const float* feature = (const float*)d_in[1];
  const float* w0  = (const float*)d_in[2];
  const float* b0  = (const float*)d_in[3];
  const float* g0  = (const float*)d_in[4];
  const float* be0 = (const float*)d_in[5];
  const float* w1  = (const float*)d_in[6];
  const float* b1  = (const float*)d_in[7];
  const float* g1  = (const float*)d_in[8];
  const float* be1 = (const float*)d_in[9];
  const float* w2  = (const float*)d_in[10];
  const float* b2  = (const float*)d_in[11];
  const float* wl  = (const float*)d_in[12];
  const float* bl  = (const float*)d_in[13];
  const float* gl  = (const float*)d_in[14];
  const float* bel = (const float*)d_in[15];
  const float* wf  = (const float*)d_in[16];
  const float* bf  = (const float*)d_in[17];
  const float* gf  = (const float*)d_in[18];
  const float* bef = (const float*)d_in[19];
  float* out = (float*)d_out;

  char* ws = (char*)d_ws;
  float*          featT = (float*)(ws + 0);          // 33.5 MB
  float*          wbuf  = (float*)(ws + 33554432);   // 33.5 MB (dead after k_agg)
  float*          part  = (float*)(ws + 33554432);   // 8 MB, reuses wbuf region
  unsigned short* aggB  = (unsigned short*)(ws + 67108864);  // 33.5 MB bf16
  unsigned short* wlB   = (unsigned short*)(ws + 134217728); // 1 MB bf16
  float*          wfT   = (float*)(ws + 136314880);  // 98 KB
  float*          nxyz  = (float*)(ws + 136429568);  // 48 KB
  int*            gidx  = (int*)  (ws + 136478720);  // 512 KB
  float*          nfT   = (float*)(ws + 137003008);  // 2 MB

  k_tf     <<<2048, 256, 0, stream>>>(feature, featT);
  k_twl    <<<512,  256, 0, stream>>>(wl, wlB);
  k_twf    <<<96,   256, 0, stream>>>(wf, wfT);
  k_fps    <<<BB,   512, 0, stream>>>(xyz, nxyz);
  k_bq_mlp <<<BB*MM, 64, 0, stream>>>(xyz, nxyz, w0,b0,g0,be0, w1,b1,g1,be1, w2,b2, gidx, wbuf);
  k_agg    <<<BB*MM, 256, 0, stream>>>(featT, wbuf, gidx, aggB);
  k_nf_part<<<256,  256, 0, stream>>>(aggB, wlB, part);
  k_nf_ep  <<<512,  256, 0, stream>>>(part, bl, gl, bel, nfT);
  k_final  <<<BB*(NN/128), 256, 0, stream>>>(xyz, nxyz, nfT, feature, wfT, bf, gf, bef, out);
}

// Round 5
// 592.581 us; speedup vs baseline: 2.0073x; 1.0398x over previous
//
#include <hip/hip_runtime.h>
#include <hip/hip_bf16.h>
#include <cstdint>
#include <cstddef>

#define BB   16
#define NN   8192
#define DD   64
#define MM   256
#define SS   32
#define OUTC 128
#define WCC  64

using short8 = __attribute__((ext_vector_type(8))) short;
using f32x4  = __attribute__((ext_vector_type(4))) float;

#ifndef __has_builtin
#define __has_builtin(x) 0
#endif
#if __has_builtin(__builtin_amdgcn_update_dpp) && __has_builtin(__builtin_amdgcn_readlane)
#define USE_DPP 1
#else
#define USE_DPP 0
#endif

__device__ __forceinline__ float bnf(float x, float g, float be){
    const float BNS = 0.99999500003749969f; // 1/sqrt(1+1e-5)
    return g * (x * BNS) + be;
}
__device__ __forceinline__ unsigned short f2bf(float f){
    __hip_bfloat16 h = __float2bfloat16(f);
    return *reinterpret_cast<unsigned short*>(&h);
}
__device__ __forceinline__ float bf2f(unsigned short u){
    return __uint_as_float(((unsigned)u) << 16);
}

// ============ merged prologue: FPS + feature->bf16 transpose + weight casts ============
// blocks 0..15: FPS | 16..2063: feat transpose | 2064..2575: wl cast | 2576..2599: wf cast
#define PRE_GRID (16 + 2048 + 512 + 24)

__global__ __launch_bounds__(256) void k_pre(const float* __restrict__ xyz, float* __restrict__ nxyz,
    const float* __restrict__ feature, unsigned short* __restrict__ featB,
    const float* __restrict__ wl, unsigned short* __restrict__ wlB,
    const float* __restrict__ wf, unsigned short* __restrict__ wfB){
  __shared__ union {
    struct {
      float sxyz[NN*3];
      float snew[MM*3];
      unsigned long long skey[2][4];
    } f;
    float tile[64][65];
  } sm;
  const int t = threadIdx.x;
  int blk = blockIdx.x;

  if (blk < 16){
    // ---------------- FPS: 256 threads, DPP reduce, 1 barrier/step ----------------
    const int b = blk;
    const float* xb = xyz + (size_t)b*NN*3;
    for (int i = t; i < NN*3; i += 256) sm.f.sxyz[i] = xb[i];
    float px[32], py[32], pz[32], dist[32];
#pragma unroll
    for (int i=0;i<32;i++){
      int id = i*256 + t;
      px[i] = xb[id*3+0]; py[i] = xb[id*3+1]; pz[i] = xb[id*3+2];
      dist[i] = 1e10f;
    }
    __syncthreads();
    float lx = sm.f.sxyz[0], ly = sm.f.sxyz[1], lz = sm.f.sxyz[2];
    if (t==0){ sm.f.snew[0]=lx; sm.f.snew[1]=ly; sm.f.snew[2]=lz; }
    for (int step=1; step<MM; ++step){
      float bv = 0.0f; int bi = NN-1;
#pragma unroll
      for (int i=0;i<32;i++){
        float dx=px[i]-lx, dy=py[i]-ly, dz=pz[i]-lz;
        float d = dx*dx + dy*dy + dz*dz;
        float nd = fminf(dist[i], d);
        dist[i] = nd;
        bool gt = nd > bv;
        bv = gt ? nd : bv;
        bi = gt ? (i*256 + t) : bi;
      }
      unsigned long long key;
#if USE_DPP
      {
        float v = bv;
        int s_;
        s_ = __builtin_amdgcn_update_dpp(__float_as_int(v), __float_as_int(v), 0x111, 0xF, 0xF, 0); v = fmaxf(v, __int_as_float(s_));
        s_ = __builtin_amdgcn_update_dpp(__float_as_int(v), __float_as_int(v), 0x112, 0xF, 0xF, 0); v = fmaxf(v, __int_as_float(s_));
        s_ = __builtin_amdgcn_update_dpp(__float_as_int(v), __float_as_int(v), 0x114, 0xF, 0xF, 0); v = fmaxf(v, __int_as_float(s_));
        s_ = __builtin_amdgcn_update_dpp(__float_as_int(v), __float_as_int(v), 0x118, 0xF, 0xF, 0); v = fmaxf(v, __int_as_float(s_));
        s_ = __builtin_amdgcn_update_dpp(__float_as_int(v), __float_as_int(v), 0x142, 0xF, 0xF, 0); v = fmaxf(v, __int_as_float(s_));
        s_ = __builtin_amdgcn_update_dpp(__float_as_int(v), __float_as_int(v), 0x143, 0xF, 0xF, 0); v = fmaxf(v, __int_as_float(s_));
        float wmax = __int_as_float(__builtin_amdgcn_readlane(__float_as_int(v), 63));
        unsigned cm = (bv == wmax) ? (unsigned)bi : 0xFFFFFFFFu;
        unsigned u_;
        u_ = (unsigned)__builtin_amdgcn_update_dpp((int)cm, (int)cm, 0x111, 0xF, 0xF, 0); cm = cm < u_ ? cm : u_;
        u_ = (unsigned)__builtin_amdgcn_update_dpp((int)cm, (int)cm, 0x112, 0xF, 0xF, 0); cm = cm < u_ ? cm : u_;
        u_ = (unsigned)__builtin_amdgcn_update_dpp((int)cm, (int)cm, 0x114, 0xF, 0xF, 0); cm = cm < u_ ? cm : u_;
        u_ = (unsigned)__builtin_amdgcn_update_dpp((int)cm, (int)cm, 0x118, 0xF, 0xF, 0); cm = cm < u_ ? cm : u_;
        u_ = (unsigned)__builtin_amdgcn_update_dpp((int)cm, (int)cm, 0x142, 0xF, 0xF, 0); cm = cm < u_ ? cm : u_;
        u_ = (unsigned)__builtin_amdgcn_update_dpp((int)cm, (int)cm, 0x143, 0xF, 0xF, 0); cm = cm < u_ ? cm : u_;
        unsigned widx = (unsigned)__builtin_amdgcn_readlane((int)cm, 63);
        key = ((unsigned long long)__float_as_uint(wmax) << 32) | (unsigned)(NN-1 - widx);
      }
#else
      key = ((unsigned long long)__float_as_uint(bv) << 32) | (unsigned)(NN-1 - bi);
#pragma unroll
      for (int off=1; off<64; off<<=1){
        unsigned long long ok = __shfl_xor(key, off, 64);
        if (ok > key) key = ok;
      }
#endif
      const int p = step & 1;
      if ((t & 63) == 0) sm.f.skey[p][t>>6] = key;
      __syncthreads();
      unsigned long long k0=sm.f.skey[p][0], k1=sm.f.skey[p][1], k2=sm.f.skey[p][2], k3=sm.f.skey[p][3];
      unsigned long long ka = k0>k1?k0:k1, kb = k2>k3?k2:k3;
      unsigned long long kw = ka>kb?ka:kb;
      const int bid = (NN-1) - (int)(unsigned)(kw & 0xFFFFFFFFull);
      lx = sm.f.sxyz[bid*3+0]; ly = sm.f.sxyz[bid*3+1]; lz = sm.f.sxyz[bid*3+2];
      if (t==0){ sm.f.snew[step*3+0]=lx; sm.f.snew[step*3+1]=ly; sm.f.snew[step*3+2]=lz; }
    }
    __syncthreads();
    for (int i = t; i < MM*3; i += 256) nxyz[(size_t)b*MM*3 + i] = sm.f.snew[i];
    return;
  }
  blk -= 16;
  if (blk < 2048){
    // ---------------- feature transpose (B,D,N) -> featB (B,N,D) bf16 ----------------
    const int b  = blk >> 7;
    const int n0 = (blk & 127) << 6;
    {
      const int d = t >> 2, j0 = (t & 3) << 4;
      const float* src = feature + ((size_t)b*DD + d)*NN + n0 + j0;
#pragma unroll
      for (int i=0;i<16;i+=4){
        float4 v = *(const float4*)(src + i);
        sm.tile[d][j0+i+0]=v.x; sm.tile[d][j0+i+1]=v.y; sm.tile[d][j0+i+2]=v.z; sm.tile[d][j0+i+3]=v.w;
      }
    }
    __syncthreads();
    {
      const int j = t >> 2, d0 = (t & 3) << 4;
      unsigned short hv[16];
#pragma unroll
      for (int i=0;i<16;i++) hv[i] = f2bf(sm.tile[d0+i][j]);
      unsigned short* dst = featB + ((size_t)b*NN + n0 + j)*64 + d0;
      *(uint4*)(dst)     = *(uint4*)(&hv[0]);
      *(uint4*)(dst + 8) = *(uint4*)(&hv[8]);
    }
    return;
  }
  blk -= 2048;
  if (blk < 512){
    int idx = (blk*256 + t)*4;
    float4 v = *(const float4*)(wl + idx);
    ushort4 h = make_ushort4(f2bf(v.x), f2bf(v.y), f2bf(v.z), f2bf(v.w));
    *(ushort4*)(wlB + idx) = h;
    return;
  }
  blk -= 512;
  {
    int idx = (blk*256 + t)*4;
    if (idx < 128*192){
      float4 v = *(const float4*)(wf + idx);
      ushort4 h = make_ushort4(f2bf(v.x), f2bf(v.y), f2bf(v.z), f2bf(v.w));
      *(ushort4*)(wfB + idx) = h;
    }
  }
}

// ---------------- ball query + 3-layer MLP (LDS-staged) ----------------
__global__ __launch_bounds__(64) void k_bq_mlp(const float* __restrict__ xyz,
    const float* __restrict__ nxyz,
    const float* __restrict__ w0, const float* __restrict__ b0,
    const float* __restrict__ g0, const float* __restrict__ be0,
    const float* __restrict__ w1, const float* __restrict__ b1,
    const float* __restrict__ g1, const float* __restrict__ be1,
    const float* __restrict__ w2, const float* __restrict__ b2,
    int* __restrict__ gidx, float* __restrict__ wbuf){
  const int bm = blockIdx.x;
  const int b  = bm >> 8;
  const int c  = threadIdx.x;
  __shared__ int   sidx[SS];
  __shared__ float sgx[3][SS];
  __shared__ float sh0[SS][WCC];
  __shared__ float sh1[SS][WCC];

  const float w0r0 = w0[c*3+0], w0r1 = w0[c*3+1], w0r2 = w0[c*3+2];
  const float b0c=b0[c], g0c=g0[c], be0c=be0[c];
  const float b1c=b1[c], g1c=g1[c], be1c=be1[c], b2c=b2[c];
  float w1r[64], w2r[64];
#pragma unroll
  for (int i=0;i<16;i++){
    float4 v = *(const float4*)(w1 + c*64 + i*4);
    w1r[i*4+0]=v.x; w1r[i*4+1]=v.y; w1r[i*4+2]=v.z; w1r[i*4+3]=v.w;
    float4 u = *(const float4*)(w2 + c*64 + i*4);
    w2r[i*4+0]=u.x; w2r[i*4+1]=u.y; w2r[i*4+2]=u.z; w2r[i*4+3]=u.w;
  }
  const float cx = nxyz[bm*3+0], cy = nxyz[bm*3+1], cz = nxyz[bm*3+2];
  const float* xb = xyz + (size_t)b*NN*3;
  const float R2 = (float)(0.4*0.4);
  int cnt = 0;
  for (int n0=0; n0<NN && cnt<SS; n0+=64){
    int n = n0 + c;
    float dx = xb[n*3+0]-cx, dy = xb[n*3+1]-cy, dz = xb[n*3+2]-cz;
    float d2 = dx*dx+dy*dy+dz*dz;
    bool in = (d2 <= R2);
    unsigned long long mk = __ballot(in);
    int rank = cnt + (int)__popcll(mk & ((1ull<<c)-1ull));
    if (in && rank < SS) sidx[rank] = n;
    cnt += (int)__popcll(mk);
  }
  int total = min(cnt, SS);
  __syncthreads();
  int i0 = sidx[0];
  if (c >= total && c < SS) sidx[c] = i0;
  __syncthreads();
  if (c < SS){
    int p = sidx[c];
    gidx[bm*SS + c] = p;
    sgx[0][c] = xb[p*3+0]-cx;
    sgx[1][c] = xb[p*3+1]-cy;
    sgx[2][c] = xb[p*3+2]-cz;
  }
  __syncthreads();
  for (int s=0;s<SS;s++){
    float pre = w0r0*sgx[0][s] + w0r1*sgx[1][s] + w0r2*sgx[2][s] + b0c;
    sh0[s][c] = fmaxf(bnf(pre, g0c, be0c), 0.f);
  }
  __syncthreads();
  for (int s=0;s<SS;s++){
    float a = b1c;
#pragma unroll
    for (int k=0;k<64;k+=4){
      float4 h = *(const float4*)(&sh0[s][k]);
      a += w1r[k]*h.x + w1r[k+1]*h.y + w1r[k+2]*h.z + w1r[k+3]*h.w;
    }
    sh1[s][c] = fmaxf(bnf(a, g1c, be1c), 0.f);
  }
  __syncthreads();
  float* wb = wbuf + (size_t)bm*SS*WCC;
  for (int s=0;s<SS;s++){
    float a = b2c;
#pragma unroll
    for (int k=0;k<64;k+=4){
      float4 h = *(const float4*)(&sh1[s][k]);
      a += w2r[k]*h.x + w2r[k+1]*h.y + w2r[k+2]*h.z + w2r[k+3]*h.w;
    }
    wb[s*WCC + c] = a;
  }
}

// ---------------- aggregation -> agg in bf16 [4096][4096] ----------------
__global__ __launch_bounds__(256) void k_agg(const unsigned short* __restrict__ featB,
                                             const float* __restrict__ wbuf,
                                             const int* __restrict__ gidx,
                                             unsigned short* __restrict__ aggB){
  const int bm = blockIdx.x;
  const int b  = bm >> 8;
  __shared__ float wt[SS][WCC];
  __shared__ int   sidx[SS];
  const int t = threadIdx.x;
  const float* wsrc = wbuf + (size_t)bm*SS*WCC;
#pragma unroll
  for (int i=0;i<8;i++){
    int li = t + i*256;
    ((float*)wt)[li] = wsrc[li];
  }
  if (t < SS) sidx[t] = gidx[bm*SS + t];
  __syncthreads();
  const int d  = t & 63;
  const int wg = t >> 6;
  float acc[16];
#pragma unroll
  for (int j=0;j<16;j++) acc[j]=0.f;
  const unsigned short* fb = featB + (size_t)b*NN*64;
  for (int s=0;s<SS;s++){
    float fv = bf2f(fb[(size_t)sidx[s]*64 + d]);
#pragma unroll
    for (int j=0;j<16;j++) acc[j] += fv * wt[s][wg*16+j];
  }
  unsigned short h[16];
#pragma unroll
  for (int j=0;j<16;j++) h[j] = f2bf(acc[j]);
  unsigned short* ab = aggB + (size_t)bm*4096 + d*64 + wg*16;
  *(uint4*)(ab)     = *(uint4*)(&h[0]);
  *(uint4*)(ab + 8) = *(uint4*)(&h[8]);
}

// ---------------- new_feature GEMM via MFMA bf16, split-K partials ----------------
__global__ __launch_bounds__(256) void k_nf_part(const unsigned short* __restrict__ aggB,
                                                 const unsigned short* __restrict__ wlB,
                                                 float* __restrict__ part){
  const int blk = blockIdx.x;
  const int rb  = blk >> 2;
  const int ks  = blk & 3;
  const int wid = threadIdx.x >> 6, lane = threadIdx.x & 63;
  const int m0 = rb*64 + wid*16;
  const int r  = lane & 15, kg = lane >> 4;
  f32x4 acc[8];
#pragma unroll
  for (int i=0;i<8;i++) acc[i] = (f32x4){0.f,0.f,0.f,0.f};
  const short* arow = (const short*)aggB + (size_t)(m0 + r)*4096 + ks*1024 + kg*8;
  const short* brow = (const short*)wlB  + (size_t)r*4096        + ks*1024 + kg*8;
#pragma unroll 4
  for (int kc=0; kc<32; kc++){
    short8 a = *(const short8*)(arow + kc*32);
#pragma unroll
    for (int ot=0; ot<8; ot++){
      short8 bfr = *(const short8*)(brow + (size_t)ot*16*4096 + kc*32);
      acc[ot] = __builtin_amdgcn_mfma_f32_16x16x32_bf16(a, bfr, acc[ot], 0, 0, 0);
    }
  }
  float* pb = part + ((size_t)ks << 19);
#pragma unroll
  for (int ot=0; ot<8; ot++){
#pragma unroll
    for (int rr=0; rr<4; rr++){
      int row = m0 + kg*4 + rr;
      pb[(size_t)row*128 + ot*16 + r] = acc[ot][rr];
    }
  }
}

// ---------------- nf epilogue: sum 4 partials + bias + bn + relu ----------------
__global__ __launch_bounds__(256) void k_nf_ep(const float* __restrict__ part,
    const float* __restrict__ bl, const float* __restrict__ gl, const float* __restrict__ bel,
    float* __restrict__ nfT){
  const int gid = blockIdx.x*256 + threadIdx.x;
  const int base = gid*4;
  const int o0 = base & 127;
  float4 s0 = *(const float4*)(part + base);
  float4 s1 = *(const float4*)(part + (1<<19) + base);
  float4 s2 = *(const float4*)(part + (2<<19) + base);
  float4 s3 = *(const float4*)(part + (3<<19) + base);
  float sum[4] = {s0.x+s1.x+s2.x+s3.x, s0.y+s1.y+s2.y+s3.y,
                  s0.z+s1.z+s2.z+s3.z, s0.w+s1.w+s2.w+s3.w};
  float ov[4];
#pragma unroll
  for (int j=0;j<4;j++){
    const int o = o0 + j;
    ov[j] = fmaxf(bnf(sum[j] + bl[o], gl[o], bel[o]), 0.f);
  }
  *(float4*)(nfT + base) = make_float4(ov[0],ov[1],ov[2],ov[3]);
}

// ---------------- fused: 3-NN interp + final conv via MFMA bf16 ----------------
__global__ __launch_bounds__(256) void k_final(const float* __restrict__ xyz,
    const float* __restrict__ nxyz, const float* __restrict__ nfT,
    const unsigned short* __restrict__ featB, const unsigned short* __restrict__ wfB,
    const float* __restrict__ bf, const float* __restrict__ gf, const float* __restrict__ bef,
    float* __restrict__ out){
  const int blk = blockIdx.x;
  const int b  = blk >> 6;
  const int n0 = (blk & 63) << 7;
  __shared__ float snew[MM*3];
  __shared__ float sw[128][3];
  __shared__ int   si[128][3];
  const int t = threadIdx.x;
  if (t < 192){
    float4 v = *(const float4*)(nxyz + (size_t)b*MM*3 + t*4);
    snew[t*4+0]=v.x; snew[t*4+1]=v.y; snew[t*4+2]=v.z; snew[t*4+3]=v.w;
  }
  __syncthreads();
  if (t < 128){
    const int n = n0 + t;
    const float x = xyz[((size_t)b*NN+n)*3+0];
    const float y = xyz[((size_t)b*NN+n)*3+1];
    const float z = xyz[((size_t)b*NN+n)*3+2];
    float d1=1e30f, d2=1e30f, d3=1e30f; int i1=0,i2=0,i3=0;
    for (int m=0;m<MM;m++){
      float dx=x-snew[m*3+0], dy=y-snew[m*3+1], dz=z-snew[m*3+2];
      float d = dx*dx+dy*dy+dz*dz;
      if (d < d3){
        if (d < d1){ d3=d2;i3=i2; d2=d1;i2=i1; d1=d;i1=m; }
        else if (d < d2){ d3=d2;i3=i2; d2=d;i2=m; }
        else { d3=d;i3=m; }
      }
    }
    float r1=1.f/(d1+1e-8f), r2=1.f/(d2+1e-8f), r3=1.f/(d3+1e-8f);
    float rs = 1.f/(r1+r2+r3);
    sw[t][0]=r1*rs; sw[t][1]=r2*rs; sw[t][2]=r3*rs;
    si[t][0]=i1; si[t][1]=i2; si[t][2]=i3;
  }
  __syncthreads();

  const int w = t >> 6, lane = t & 63;
  const int r = lane & 15, kg = lane >> 4;
  // hoist interp params for this lane's 8 n-columns
  float wA[8][3]; int iA[8][3];
#pragma unroll
  for (int nt=0;nt<8;nt++){
    int n = nt*16 + r;
    wA[nt][0]=sw[n][0]; wA[nt][1]=sw[n][1]; wA[nt][2]=sw[n][2];
    iA[nt][0]=si[n][0]*128; iA[nt][1]=si[n][1]*128; iA[nt][2]=si[n][2]*128;
  }
  const float* nfb = nfT + (size_t)b*MM*128;
  const unsigned short* fbB = featB + ((size_t)b*NN + n0)*64;
  const unsigned short* wfRow0 = wfB + (size_t)(w*32 +      r)*192 + kg*8;
  const unsigned short* wfRow1 = wfB + (size_t)(w*32 + 16 + r)*192 + kg*8;
  f32x4 acc[2][8];
#pragma unroll
  for (int i=0;i<2;i++)
#pragma unroll
    for (int j=0;j<8;j++) acc[i][j] = (f32x4){0.f,0.f,0.f,0.f};

#pragma unroll
  for (int c=0;c<6;c++){
    short8 a0 = *(const short8*)(wfRow0 + c*32);
    short8 a1 = *(const short8*)(wfRow1 + c*32);
    if (c < 4){
      const int k8 = c*32 + kg*8;
#pragma unroll
      for (int nt=0;nt<8;nt++){
        const float* p0 = nfb + iA[nt][0] + k8;
        const float* p1 = nfb + iA[nt][1] + k8;
        const float* p2 = nfb + iA[nt][2] + k8;
        float4 xa = *(const float4*)(p0), xb4 = *(const float4*)(p0+4);
        float4 ya = *(const float4*)(p1), yb4 = *(const float4*)(p1+4);
        float4 za = *(const float4*)(p2), zb4 = *(const float4*)(p2+4);
        const float w0v=wA[nt][0], w1v=wA[nt][1], w2v=wA[nt][2];
        float e0 = w0v*xa.x + w1v*ya.x + w2v*za.x;
        float e1 = w0v*xa.y + w1v*ya.y + w2v*za.y;
        float e2 = w0v*xa.z + w1v*ya.z + w2v*za.z;
        float e3 = w0v*xa.w + w1v*ya.w + w2v*za.w;
        float e4 = w0v*xb4.x + w1v*yb4.x + w2v*zb4.x;
        float e5 = w0v*xb4.y + w1v*yb4.y + w2v*zb4.y;
        float e6 = w0v*xb4.z + w1v*yb4.z + w2v*zb4.z;
        float e7 = w0v*xb4.w + w1v*yb4.w + w2v*zb4.w;
        short8 bfr = { (short)f2bf(e0), (short)f2bf(e1), (short)f2bf(e2), (short)f2bf(e3),
                       (short)f2bf(e4), (short)f2bf(e5), (short)f2bf(e6), (short)f2bf(e7) };
        acc[0][nt] = __builtin_amdgcn_mfma_f32_16x16x32_bf16(a0, bfr, acc[0][nt], 0, 0, 0);
        acc[1][nt] = __builtin_amdgcn_mfma_f32_16x16x32_bf16(a1, bfr, acc[1][nt], 0, 0, 0);
      }
    } else {
      const int d8 = (c-4)*32 + kg*8;
#pragma unroll
      for (int nt=0;nt<8;nt++){
        short8 bfr = *(const short8*)(fbB + (size_t)(nt*16 + r)*64 + d8);
        acc[0][nt] = __builtin_amdgcn_mfma_f32_16x16x32_bf16(a0, bfr, acc[0][nt], 0, 0, 0);
        acc[1][nt] = __builtin_amdgcn_mfma_f32_16x16x32_bf16(a1, bfr, acc[1][nt], 0, 0, 0);
      }
    }
  }
  // epilogue: D row = o = w*32 + ot*16 + kg*4 + rr ; col = n = nt*16 + r
#pragma unroll
  for (int ot=0; ot<2; ot++){
#pragma unroll
    for (int rr=0; rr<4; rr++){
      const int o = w*32 + ot*16 + kg*4 + rr;
      const float bfo = bf[o], gfo = gf[o], befo = bef[o];
      float* dst = out + ((size_t)b*OUTC + o)*NN + n0 + r;
#pragma unroll
      for (int nt=0;nt<8;nt++){
        float val = fmaxf(bnf(acc[ot][nt][rr] + bfo, gfo, befo), 0.f);
        dst[nt*16] = val;
      }
    }
  }
}

extern "C" void kernel_launch(void* const* d_in, const int* in_sizes, int n_in,
                              void* d_out, int out_size, void* d_ws, size_t ws_size,
                              hipStream_t stream){
  const float* xyz     = (const float*)d_in[0];
  const float* feature = (const float*)d_in[1];
  const float* w0  = (const float*)d_in[2];
  const float* b0  = (const float*)d_in[3];
  const float* g0  = (const float*)d_in[4];
  const float* be0 = (const float*)d_in[5];
  const float* w1  = (const float*)d_in[6];
  const float* b1  = (const float*)d_in[7];
  const float* g1  = (const float*)d_in[8];
  const float* be1 = (const float*)d_in[9];
  const float* w2  = (const float*)d_in[10];
  const float* b2  = (const float*)d_in[11];
  const float* wl  = (const float*)d_in[12];
  const float* bl  = (const float*)d_in[13];
  const float* gl  = (const float*)d_in[14];
  const float* bel = (const float*)d_in[15];
  const float* wf  = (const float*)d_in[16];
  const float* bf  = (const float*)d_in[17];
  const float* gf  = (const float*)d_in[18];
  const float* bef = (const float*)d_in[19];
  float* out = (float*)d_out;

  char* ws = (char*)d_ws;
  unsigned short* featB = (unsigned short*)(ws + 0);          // 16 MB
  float*          wbuf  = (float*)(ws + 16777216);            // 33.5 MB (dead after k_agg)
  float*          part  = (float*)(ws + 16777216);            // 8 MB, reuses wbuf region
  unsigned short* aggB  = (unsigned short*)(ws + 50331648);   // 33.5 MB
  unsigned short* wlB   = (unsigned short*)(ws + 83886080);   // 1 MB
  unsigned short* wfB   = (unsigned short*)(ws + 84934656);   // 48 KB
  float*          nxyz  = (float*)(ws + 84983808);            // 48 KB
  int*            gidx  = (int*)  (ws + 85032960);            // 512 KB
  float*          nfT   = (float*)(ws + 85557248);            // 2 MB

  k_pre    <<<PRE_GRID, 256, 0, stream>>>(xyz, nxyz, feature, featB, wl, wlB, wf, wfB);
  k_bq_mlp <<<BB*MM, 64, 0, stream>>>(xyz, nxyz, w0,b0,g0,be0, w1,b1,g1,be1, w2,b2, gidx, wbuf);
  k_agg    <<<BB*MM, 256, 0, stream>>>(featB, wbuf, gidx, aggB);
  k_nf_part<<<256,  256, 0, stream>>>(aggB, wlB, part);
  k_nf_ep  <<<512,  256, 0, stream>>>(part, bl, gl, bel, nfT);
  k_final  <<<BB*(NN/128), 256, 0, stream>>>(xyz, nxyz, nfT, featB, wfB, bf, gf, bef, out);
}